// Round 7
// baseline (597.615 us; speedup 1.0000x reference)
//
#include <hip/hip_runtime.h>

#define LEAKY 0.2f
#define BN_EPS 1e-5f
#define BCHUNK 8192

typedef __bf16 v8bf __attribute__((ext_vector_type(8)));
typedef float v16f __attribute__((ext_vector_type(16)));
typedef float v2f __attribute__((ext_vector_type(2)));

// ---------- wave helpers (wave64) ----------
__device__ __forceinline__ float wsum(float v) {
#pragma unroll
  for (int o = 32; o > 0; o >>= 1) v += __shfl_xor(v, o, 64);
  return v;
}

// packed-bf16: dword holds feat2j (low16) and feat2j+1 (high16)
__device__ __forceinline__ float blo(unsigned u) { return __uint_as_float(u << 16); }
__device__ __forceinline__ float bhi(unsigned u) { return __uint_as_float(u & 0xffff0000u); }
__device__ __forceinline__ v2f bpair(unsigned u) {
  v2f r; r.x = __uint_as_float(u << 16); r.y = __uint_as_float(u & 0xffff0000u); return r;
}
__device__ __forceinline__ unsigned pack_bf16(float a, float b) {
  unsigned ua = __float_as_uint(a), ub = __float_as_uint(b);
  ua = (ua + 0x7fffu + ((ua >> 16) & 1u)) >> 16;
  ub = (ub + 0x7fffu + ((ub >> 16) & 1u)) >> 16;
  return ua | (ub << 16);
}
__device__ __forceinline__ unsigned short bf16of(float a) {
  unsigned ua = __float_as_uint(a);
  return (unsigned short)((ua + 0x7fffu + ((ua >> 16) & 1u)) >> 16);
}

// D = c + a.lo*b.lo + a.hi*b.hi  (bf16 pairs, f32 accumulate)
__device__ __forceinline__ float dot2bf(unsigned a, unsigned b, float c) {
  asm("v_dot2_f32_bf16 %0, %1, %2, %0" : "+v"(c) : "v"(a), "v"(b));
  return c;
}
// (lo16(u1), lo16(u2)) packed into one dword
__device__ __forceinline__ unsigned permlo(unsigned u1, unsigned u2) {
  return __builtin_amdgcn_perm(u2, u1, 0x05040100u);
}
// (hi16(u1), hi16(u2)) packed into one dword
__device__ __forceinline__ unsigned permhi(unsigned u1, unsigned u2) {
  return __builtin_amdgcn_perm(u2, u1, 0x07060302u);
}

// edge_index may be int64 (reference dtype) or int32 (JAX x64 disabled).
__device__ __forceinline__ int edge_at(const void* ei, int is64, long long i) {
  return is64 ? (int)((const long long*)ei)[i] : ((const int*)ei)[i];
}

// =================== device bodies (shared by merged kernels) ===================

// histA: per-dst global histogram (cnt[N] int, pre-zeroed). lds: 1 int for flag.
__device__ __forceinline__ void histA_body(int blk, const void* ei, int N, int E, int M,
                                           int* cnt, int* sflag) {
  int tid = threadIdx.x;
  if (tid < 64) {
    const long long* p = (const long long*)ei;
    long long v = p[tid];
    int bad = (v < 0 || v >= (long long)N) ? 1 : 0;
    unsigned long long mres = __ballot(bad);
    if (tid == 0) *sflag = (mres == 0ull) ? 1 : 0;
  }
  __syncthreads();
  int is64 = *sflag;
  long long base = (long long)blk * BCHUNK;
  int c = (int)min((long long)BCHUNK, (long long)M - base);
  for (int i = tid; i < c; i += 256) {
    long long g = base + i;
    int d = (g < E) ? edge_at(ei, is64, (long long)E + g) : (int)(g - E);
    atomicAdd(&cnt[d], 1);
  }
}

// scat: scatter src directly into col via per-dst cursor (cur[N] from scan).
__device__ __forceinline__ void scat_body(int blk, const void* ei, int N, int E, int M,
                                          int* cur, int* col, int* sflag) {
  int tid = threadIdx.x;
  if (tid < 64) {
    const long long* p = (const long long*)ei;
    long long v = p[tid];
    int bad = (v < 0 || v >= (long long)N) ? 1 : 0;
    unsigned long long mres = __ballot(bad);
    if (tid == 0) *sflag = (mres == 0ull) ? 1 : 0;
  }
  __syncthreads();
  int is64 = *sflag;
  long long base = (long long)blk * BCHUNK;
  int c = (int)min((long long)BCHUNK, (long long)M - base);
  for (int i = tid; i < c; i += 256) {
    long long g = base + i;
    int s, d;
    if (g < E) { s = edge_at(ei, is64, g); d = edge_at(ei, is64, (long long)E + g); }
    else       { s = d = (int)(g - E); }
    int pos = atomicAdd(&cur[d], 1);
    col[pos] = s;
  }
}

#define MM_SMEM (32 * 136 * 2 + 128 * 4 + 128 * 4)  // Al + scl + sht = 9728 B

// MFMA matmul + es/ed via 9th B-tile (wave 0). smem: MM_SMEM bytes, 16-aligned.
__device__ __forceinline__ void mm_body(int blk, const void* xin, int packed,
    const float* stats, const float* gamma, const float* beta,
    const unsigned short* Bp, unsigned* hb, unsigned* linp,
    float* es, float* ed, int N, char* smem) {
  unsigned short* Al = (unsigned short*)smem;                  // 32*136
  float* scl_s = (float*)(smem + 8704);
  float* sht_s = (float*)(smem + 8704 + 512);
  int tid = threadIdx.x;
  int lane = tid & 63;
  int w = tid >> 6;
  int rowBase = blk * 32;

  if (tid < 128) {
    float s = 0.f, s2 = 0.f;
#pragma unroll
    for (int r = 0; r < 8; ++r) {
      s += stats[r * 256 + tid];
      s2 += stats[r * 256 + 128 + tid];
    }
    float inv_n = 1.0f / (float)N;
    float mu = s * inv_n;
    float var = s2 * inv_n - mu * mu;
    float rs = rsqrtf(var + BN_EPS);
    float sc = gamma[tid] * rs;
    scl_s[tid] = sc;
    sht_s[tid] = beta[tid] - mu * sc;
  }

  v8bf bfrag[2][8];
#pragma unroll
  for (int t = 0; t < 2; ++t)
#pragma unroll
    for (int s = 0; s < 8; ++s) {
      int fi = ((2 * w + t) * 8 + s) * 64 + lane;
      bfrag[t][s] = *(const v8bf*)&Bp[(size_t)fi * 8];
    }
  __syncthreads();

  if (!packed) {
    const float* x = (const float*)xin;
    for (int q = tid; q < 32 * 32; q += 256) {
      int r = q >> 5, k4 = (q & 31) * 4;
      int row = rowBase + r;
      float4 v = make_float4(0.f, 0.f, 0.f, 0.f);
      if (row < N) v = *(const float4*)&x[(size_t)row * 128 + k4];
      unsigned p0 = pack_bf16(v.x * scl_s[k4] + sht_s[k4], v.y * scl_s[k4 + 1] + sht_s[k4 + 1]);
      unsigned p1 = pack_bf16(v.z * scl_s[k4 + 2] + sht_s[k4 + 2], v.w * scl_s[k4 + 3] + sht_s[k4 + 3]);
      *(uint2*)&Al[r * 136 + k4] = make_uint2(p0, p1);
    }
  } else {
    const unsigned* xp = (const unsigned*)xin;
    for (int q = tid; q < 32 * 16; q += 256) {
      int r = q >> 4, g = q & 15;
      int row = rowBase + r;
      uint4 u = make_uint4(0u, 0u, 0u, 0u);
      if (row < N) u = *(const uint4*)&xp[(size_t)row * 64 + g * 4];
      int f = g * 8;
      uint4 o;
      o.x = pack_bf16(blo(u.x) * scl_s[f] + sht_s[f], bhi(u.x) * scl_s[f + 1] + sht_s[f + 1]);
      o.y = pack_bf16(blo(u.y) * scl_s[f + 2] + sht_s[f + 2], bhi(u.y) * scl_s[f + 3] + sht_s[f + 3]);
      o.z = pack_bf16(blo(u.z) * scl_s[f + 4] + sht_s[f + 4], bhi(u.z) * scl_s[f + 5] + sht_s[f + 5]);
      o.w = pack_bf16(blo(u.w) * scl_s[f + 6] + sht_s[f + 6], bhi(u.w) * scl_s[f + 7] + sht_s[f + 7]);
      *(uint4*)&Al[r * 136 + f] = o;
    }
  }
  __syncthreads();

  int m = lane & 31, half = lane >> 5;
  v8bf afrag[8];
#pragma unroll
  for (int s = 0; s < 8; ++s)
    afrag[s] = *(const v8bf*)&Al[m * 136 + s * 16 + half * 8];

  v16f acc0 = {}, acc1 = {};
#pragma unroll
  for (int s = 0; s < 8; ++s) {
    acc0 = __builtin_amdgcn_mfma_f32_32x32x16_bf16(afrag[s], bfrag[0][s], acc0, 0, 0, 0);
    acc1 = __builtin_amdgcn_mfma_f32_32x32x16_bf16(afrag[s], bfrag[1][s], acc1, 0, 0, 0);
  }

  v16f acc2 = {};
  if (w == 0) {
#pragma unroll
    for (int s = 0; s < 8; ++s) {
      v8bf besf = *(const v8bf*)&Bp[(size_t)((64 + s) * 64 + lane) * 8];
      acc2 = __builtin_amdgcn_mfma_f32_32x32x16_bf16(afrag[s], besf, acc2, 0, 0, 0);
    }
  }

  int mlo = half * 4;
  int t0 = 2 * w, t1 = 2 * w + 1;
#pragma unroll
  for (int r = 0; r < 16; ++r) {
    int row = (r & 3) + 8 * (r >> 2) + mlo;
    int node = rowBase + row;
    float a0 = acc0[r], a1 = acc1[r];
    float b0 = __shfl_xor(a0, 1, 64);
    float b1 = __shfl_xor(a1, 1, 64);
    if (node < N && !(lane & 1)) {
      if (t0 < 4) {
        hb[(size_t)node * 64 + (t0 * 16 + (m >> 1))] = pack_bf16(a0, b0);
        hb[(size_t)node * 64 + (t1 * 16 + (m >> 1))] = pack_bf16(a1, b1);
      } else {
        linp[(size_t)node * 64 + ((t0 - 4) * 16 + (m >> 1))] = pack_bf16(a0, b0);
        linp[(size_t)node * 64 + ((t1 - 4) * 16 + (m >> 1))] = pack_bf16(a1, b1);
      }
    }
    if (w == 0 && m < 4 && node < N) {
      float v = acc2[r];
      if (m < 2) es[2 * node + (m & 1)] = v;
      else       ed[2 * node + (m & 1)] = v;
    }
  }
}

// =================== kernels ===================

// K1: prep (Bp tiles 0-8, Wesed->tile8, layer-1 BN stats) UNION histA.
// blocks [0,34): weight prep; [34,1058): stats; [1058, 1058+nblk): histA.
__global__ __launch_bounds__(256) void k_prepA(
    const float* __restrict__ W1, const float* __restrict__ LW1,
    const float* __restrict__ W2, const float* __restrict__ LW2,
    const float* __restrict__ as1, const float* __restrict__ ad1,
    const float* __restrict__ as2, const float* __restrict__ ad2,
    const float* __restrict__ x, int N,
    unsigned short* __restrict__ Bp1, unsigned short* __restrict__ Bp2,
    float* __restrict__ stats1,
    const void* ei, int E, int M, int nblk, int* cnt) {
  __shared__ __align__(16) int lds[1025];
  int blk = blockIdx.x;
  int tid = threadIdx.x;
  if (blk >= 1058) { histA_body(blk - 1058, ei, N, E, M, cnt, lds + 1024); return; }
  if (blk >= 34) {
    int b = blk - 34;  // 0..1023
    int f = tid & 127;
    int half = tid >> 7;
    float s = 0.f, s2 = 0.f;
    for (int r = b + half * 1024; r < N; r += 2048) {
      float v = x[(size_t)r * 128 + f];
      s += v; s2 += v * v;
    }
    float* rep = stats1 + (size_t)(b & 7) * 256;
    atomicAdd(&rep[f], s);
    atomicAdd(&rep[128 + f], s2);
    return;
  }
  if (blk >= 32) {
    // tile 8: es/ed columns in B-fragment order
    float (*wes)[4] = (float(*)[4])lds;  // 128x4 floats = 2 KB
    const float* W = (blk == 32) ? W1 : W2;
    const float* as_ = (blk == 32) ? as1 : as2;
    const float* ad_ = (blk == 32) ? ad1 : ad2;
    unsigned short* Bp = (blk == 32) ? Bp1 : Bp2;
#pragma unroll
    for (int it = 0; it < 2; ++it) {
      int k = tid & 127;
      int c = (tid >> 7) + 2 * it;
      const float* a = (c < 2) ? as_ : ad_;
      int hb2 = (c & 1) * 64;
      float sum = 0.f;
      for (int f = 0; f < 64; ++f) sum += W[k * 128 + hb2 + f] * a[hb2 + f];
      wes[k][c] = sum;
    }
    __syncthreads();
    for (int fr = tid; fr < 512; fr += 256) {
      int lane = fr & 63, s = fr >> 6;
      int n = lane & 31;
      int k0 = s * 16 + (lane >> 5) * 8;
      unsigned short tb[8];
#pragma unroll
      for (int j = 0; j < 8; ++j)
        tb[j] = bf16of((n < 4) ? wes[k0 + j][n] : 0.f);
      uint4 pk;
      pk.x = (unsigned)tb[0] | ((unsigned)tb[1] << 16);
      pk.y = (unsigned)tb[2] | ((unsigned)tb[3] << 16);
      pk.z = (unsigned)tb[4] | ((unsigned)tb[5] << 16);
      pk.w = (unsigned)tb[6] | ((unsigned)tb[7] << 16);
      int fi = (64 + s) * 64 + lane;
      *(uint4*)&Bp[(size_t)fi * 8] = pk;
    }
    return;
  }
  const float* W  = (blk < 16) ? W1 : W2;
  const float* LW = (blk < 16) ? LW1 : LW2;
  unsigned short* Bp = (blk < 16) ? Bp1 : Bp2;
  int fi = (blk & 15) * 256 + tid;  // 4096 frags (tiles 0-7)
  int lane = fi & 63, s = (fi >> 6) & 7, t = fi >> 9;
  int n = t * 32 + (lane & 31);
  int k0 = s * 16 + (lane >> 5) * 8;
  unsigned short tb[8];
#pragma unroll
  for (int j = 0; j < 8; ++j) {
    int k = k0 + j;
    float v = (n < 128) ? W[k * 128 + n] : LW[k * 128 + (n - 128)];
    tb[j] = bf16of(v);
  }
  uint4 pk;
  pk.x = (unsigned)tb[0] | ((unsigned)tb[1] << 16);
  pk.y = (unsigned)tb[2] | ((unsigned)tb[3] << 16);
  pk.z = (unsigned)tb[4] | ((unsigned)tb[5] << 16);
  pk.w = (unsigned)tb[6] | ((unsigned)tb[7] << 16);
  *(uint4*)&Bp[(size_t)fi * 8] = pk;
}

// exclusive scan of cnt[0..Nn) -> rowptr[0..Nn) and cur copy; rowptr[Nn]=M.
__global__ __launch_bounds__(1024) void k_binScan(const int* __restrict__ cnt, int Nn, int M,
                                                  int* __restrict__ rowptr,
                                                  int* __restrict__ cur) {
  __shared__ int part[1024];
  int tid = threadIdx.x;
  int per = (Nn + 1023) / 1024;
  int lo = tid * per;
  int hi = lo + per; if (hi > Nn) hi = Nn;
  int s = 0;
  for (int i = lo; i < hi; ++i) s += cnt[i];
  part[tid] = s;
  __syncthreads();
  for (int off = 1; off < 1024; off <<= 1) {
    int add = (tid >= off) ? part[tid - off] : 0;
    __syncthreads();
    part[tid] += add;
    __syncthreads();
  }
  int run = (tid == 0) ? 0 : part[tid - 1];
  for (int i = lo; i < hi; ++i) {
    int c = cnt[i];
    rowptr[i] = run;
    cur[i] = run;
    run += c;
  }
  if (tid == 1023) rowptr[Nn] = M;
}

// K3: layer-1 MFMA matmul UNION scat. blocks [0,gmm): mm; [gmm, gmm+nblk): scat.
__global__ __launch_bounds__(256) void k_mmC(
    const void* __restrict__ xin, int packed,
    const float* __restrict__ stats, const float* __restrict__ gamma, const float* __restrict__ beta,
    const unsigned short* __restrict__ Bp,
    unsigned* __restrict__ hb, unsigned* __restrict__ linp,
    float* __restrict__ es, float* __restrict__ ed, int N, int gmm,
    const void* ei, int E, int M, int nblk, int* cur, int* col) {
  __shared__ __align__(16) char smem[MM_SMEM];
  int blk = blockIdx.x;
  if (blk < gmm) {
    mm_body(blk, xin, packed, stats, gamma, beta, Bp, hb, linp, es, ed, N, smem);
  } else {
    scat_body(blk - gmm, ei, N, E, M, cur, col, (int*)smem);
  }
}

// standalone mm (layer 2)
__global__ __launch_bounds__(256) void k_mm(
    const void* __restrict__ xin, int packed,
    const float* __restrict__ stats, const float* __restrict__ gamma, const float* __restrict__ beta,
    const unsigned short* __restrict__ Bp,
    unsigned* __restrict__ hb, unsigned* __restrict__ linp,
    float* __restrict__ es, float* __restrict__ ed, int N) {
  __shared__ __align__(16) char smem[MM_SMEM];
  mm_body(blockIdx.x, xin, packed, stats, gamma, beta, Bp, hb, linp, es, ed, N, smem);
}

// ---------- BatchNorm stats for packed-bf16 input (layers 2/3) ----------
__global__ __launch_bounds__(128) void k_bnstats(const unsigned* __restrict__ xp,
                                                 int N, float* sums) {
  int f = threadIdx.x;
  int q = f >> 1, hi = f & 1;
  float s = 0.f, s2 = 0.f;
  for (int r = blockIdx.x; r < N; r += gridDim.x) {
    unsigned u = xp[(size_t)r * 64 + q];
    float v = hi ? bhi(u) : blo(u);
    s += v; s2 += v * v;
  }
  float* rep = sums + (size_t)(blockIdx.x & 7) * 256;
  atomicAdd(&rep[f], s);
  atomicAdd(&rep[128 + f], s2);
}

// ---------- single-pass edge aggregation + combine; one wave per dst ----------
// Phase-split + perm/dot2; 16 edges/iter main loop (4 gathers in flight).
__global__ __launch_bounds__(256) void k_agg(
    const int* __restrict__ rowptr, const int* __restrict__ col,
    const float* __restrict__ es, const float* __restrict__ ed,
    const unsigned* __restrict__ hb, const unsigned* __restrict__ linp,
    const float* __restrict__ lb, const float* __restrict__ gb,
    unsigned* __restrict__ xoutp, int N) {
  __shared__ unsigned short phb[4][2][64];  // p (bf16) per head, per wave
  __shared__ unsigned obuf[4][64];          // hb dword offsets, per wave
  int lane = threadIdx.x & 63;
  int w = threadIdx.x >> 6;
  int d = blockIdx.x * 4 + w;
  if (d >= N) return;
  int start = rowptr[d], end = rowptr[d + 1];
  v2f edv = *(const v2f*)&ed[2 * d];
  int q = lane >> 4;   // edge-pair group 0..3
  int m = lane & 15;   // feats 8m..8m+7
  int head_hi = m >= 8;
  v2f zero = {0.f, 0.f};
  v2f lk = {LEAKY, LEAKY};

  v2f acc[4] = {zero, zero, zero, zero};
  v2f spv = zero;                       // per-lane softmax denom partial (both heads)
  unsigned short* ph = &phb[w][0][0];
  unsigned* oo = obuf[w];
  int hoff = head_hi ? 64 : 0;

  for (int base = start; base < end; base += 64) {
    int cnt = end - base; if (cnt > 64) cnt = 64;
    // ---- phase 1: p for up to 64 edges, one per lane (exp computed once/edge) ----
    {
      int valid = lane < cnt;
      int s = col[valid ? base + lane : base];
      v2f ev = *(const v2f*)&es[2 * s];
      v2f e = ev + edv;
      v2f le = __builtin_elementwise_max(e, zero) + lk * __builtin_elementwise_min(e, zero);
      v2f p; p.x = __expf(le.x); p.y = __expf(le.y);
      if (!valid) p = zero;             // zero-pad slots [cnt,64): no contribution
      spv += p;
      ph[lane] = bf16of(p.x);
      ph[64 + lane] = bf16of(p.y);
      oo[lane] = (unsigned)s * 64u;     // dword offset of hb row (clamped s is valid)
    }
    // same wave: LDS writes above are ordered before reads below (no barrier needed)
    // ---- phase 2 main: 16 edges/iter, 4 gathers in flight per lane ----
    int i = 0;
    for (; i + 16 <= cnt; i += 16) {
      int e1 = i + 2 * q;               // pair A
      int e2 = i + 8 + 2 * q;           // pair B
      unsigned fpA = *(const unsigned*)&ph[hoff + e1];
      unsigned fpB = *(const unsigned*)&ph[hoff + e2];
      uint2 oA = *(const uint2*)&oo[e1];
      uint2 oB = *(const uint2*)&oo[e2];
      uint4 u1 = *(const uint4*)&hb[(size_t)oA.x + m * 4];
      uint4 u2 = *(const uint4*)&hb[(size_t)oA.y + m * 4];
      uint4 u3 = *(const uint4*)&hb[(size_t)oB.x + m * 4];
      uint4 u4 = *(const uint4*)&hb[(size_t)oB.y + m * 4];
      acc[0].x = dot2bf(fpA, permlo(u1.x, u2.x), acc[0].x);
      acc[0].y = dot2bf(fpA, permhi(u1.x, u2.x), acc[0].y);
      acc[1].x = dot2bf(fpA, permlo(u1.y, u2.y), acc[1].x);
      acc[1].y = dot2bf(fpA, permhi(u1.y, u2.y), acc[1].y);
      acc[2].x = dot2bf(fpA, permlo(u1.z, u2.z), acc[2].x);
      acc[2].y = dot2bf(fpA, permhi(u1.z, u2.z), acc[2].y);
      acc[3].x = dot2bf(fpA, permlo(u1.w, u2.w), acc[3].x);
      acc[3].y = dot2bf(fpA, permhi(u1.w, u2.w), acc[3].y);
      acc[0].x = dot2bf(fpB, permlo(u3.x, u4.x), acc[0].x);
      acc[0].y = dot2bf(fpB, permhi(u3.x, u4.x), acc[0].y);
      acc[1].x = dot2bf(fpB, permlo(u3.y, u4.y), acc[1].x);
      acc[1].y = dot2bf(fpB, permhi(u3.y, u4.y), acc[1].y);
      acc[2].x = dot2bf(fpB, permlo(u3.z, u4.z), acc[2].x);
      acc[2].y = dot2bf(fpB, permhi(u3.z, u4.z), acc[2].y);
      acc[3].x = dot2bf(fpB, permlo(u3.w, u4.w), acc[3].x);
      acc[3].y = dot2bf(fpB, permhi(u3.w, u4.w), acc[3].y);
    }
    // ---- phase 2 remainder: 8 edges/iter (p zero-padded beyond cnt) ----
    for (; i < cnt; i += 8) {
      int e1 = i + 2 * q;               // e1 <= 63 always (i <= 56)
      unsigned fp = *(const unsigned*)&ph[hoff + e1];
      uint2 ofs = *(const uint2*)&oo[e1];
      uint4 u1 = *(const uint4*)&hb[(size_t)ofs.x + m * 4];
      uint4 u2 = *(const uint4*)&hb[(size_t)ofs.y + m * 4];
      acc[0].x = dot2bf(fp, permlo(u1.x, u2.x), acc[0].x);
      acc[0].y = dot2bf(fp, permhi(u1.x, u2.x), acc[0].y);
      acc[1].x = dot2bf(fp, permlo(u1.y, u2.y), acc[1].x);
      acc[1].y = dot2bf(fp, permhi(u1.y, u2.y), acc[1].y);
      acc[2].x = dot2bf(fp, permlo(u1.z, u2.z), acc[2].x);
      acc[2].y = dot2bf(fp, permhi(u1.z, u2.z), acc[2].y);
      acc[3].x = dot2bf(fp, permlo(u1.w, u2.w), acc[3].x);
      acc[3].y = dot2bf(fp, permhi(u1.w, u2.w), acc[3].y);
    }
  }
  // reduce acc across quarters
#pragma unroll
  for (int k = 0; k < 4; ++k) {
    acc[k].x += __shfl_xor(acc[k].x, 16, 64);
    acc[k].x += __shfl_xor(acc[k].x, 32, 64);
    acc[k].y += __shfl_xor(acc[k].y, 16, 64);
    acc[k].y += __shfl_xor(acc[k].y, 32, 64);
  }
  // reduce softmax denom across all 64 lanes (one edge per lane in phase 1)
#pragma unroll
  for (int o = 1; o < 64; o <<= 1) {
    spv.x += __shfl_xor(spv.x, o, 64);
    spv.y += __shfl_xor(spv.y, o, 64);
  }

  if (q == 0) {
    float inv = 1.0f / (head_hi ? spv.y : spv.x);
    uint4 lv = *(const uint4*)&linp[(size_t)d * 64 + m * 4];
    int f8 = 8 * m;
    float4 lb0 = *(const float4*)&lb[f8], lb1 = *(const float4*)&lb[f8 + 4];
    float4 gb0 = *(const float4*)&gb[f8], gb1 = *(const float4*)&gb[f8 + 4];
    float v0 = blo(lv.x) + lb0.x + acc[0].x * inv + gb0.x;
    float v1 = bhi(lv.x) + lb0.y + acc[0].y * inv + gb0.y;
    float v2 = blo(lv.y) + lb0.z + acc[1].x * inv + gb0.z;
    float v3 = bhi(lv.y) + lb0.w + acc[1].y * inv + gb0.w;
    float v4 = blo(lv.z) + lb1.x + acc[2].x * inv + gb1.x;
    float v5 = bhi(lv.z) + lb1.y + acc[2].y * inv + gb1.y;
    float v6 = blo(lv.w) + lb1.z + acc[3].x * inv + gb1.z;
    float v7 = bhi(lv.w) + lb1.w + acc[3].y * inv + gb1.w;
    v0 = v0 > 0.f ? v0 : 0.f; v1 = v1 > 0.f ? v1 : 0.f;
    v2 = v2 > 0.f ? v2 : 0.f; v3 = v3 > 0.f ? v3 : 0.f;
    v4 = v4 > 0.f ? v4 : 0.f; v5 = v5 > 0.f ? v5 : 0.f;
    v6 = v6 > 0.f ? v6 : 0.f; v7 = v7 > 0.f ? v7 : 0.f;
    uint4 o;
    o.x = pack_bf16(v0, v1); o.y = pack_bf16(v2, v3);
    o.z = pack_bf16(v4, v5); o.w = pack_bf16(v6, v7);
    *(uint4*)&xoutp[(size_t)d * 64 + m * 4] = o;
  }
}

// ---------- layer 3: BN(inline, 8-replica stats) + tiny matmul + es/ed ----------
__global__ __launch_bounds__(256) void k_l3node(
    const unsigned* __restrict__ xp,
    const float* __restrict__ stats, const float* __restrict__ gamma, const float* __restrict__ beta,
    const float* __restrict__ W3, const float* __restrict__ LW3,
    const float* __restrict__ as3, const float* __restrict__ ad3,
    float* h3, float* lin3, float* es3, float* ed3, int N) {
  int lane = threadIdx.x & 63;
  int n = blockIdx.x * 4 + (threadIdx.x >> 6);
  if (n >= N) return;
  float inv_n = 1.0f / (float)N;
  int f0 = lane, f1 = 64 + lane;
  float su0 = 0.f, sq0 = 0.f, su1 = 0.f, sq1 = 0.f;
#pragma unroll
  for (int r = 0; r < 8; ++r) {
    su0 += stats[r * 256 + f0];  sq0 += stats[r * 256 + 128 + f0];
    su1 += stats[r * 256 + f1];  sq1 += stats[r * 256 + 128 + f1];
  }
  float mu0 = su0 * inv_n;
  float var0 = sq0 * inv_n - mu0 * mu0;
  float rs0 = rsqrtf(var0 + BN_EPS);
  float sc0 = gamma[f0] * rs0, sh0 = beta[f0] - mu0 * sc0;
  float mu1 = su1 * inv_n;
  float var1 = sq1 * inv_n - mu1 * mu1;
  float rs1 = rsqrtf(var1 + BN_EPS);
  float sc1 = gamma[f1] * rs1, sh1 = beta[f1] - mu1 * sc1;

  unsigned ua = xp[(size_t)n * 64 + (lane >> 1)];
  unsigned ub = xp[(size_t)n * 64 + 32 + (lane >> 1)];
  float xv0 = (lane & 1) ? bhi(ua) : blo(ua);
  float xv1 = (lane & 1) ? bhi(ub) : blo(ub);
  float xn0 = xv0 * sc0 + sh0;
  float xn1 = xv1 * sc1 + sh1;

  float2 w0 = *(const float2*)&W3[lane * 2];
  float2 w1 = *(const float2*)&W3[(64 + lane) * 2];
  float2 l0 = *(const float2*)&LW3[lane * 2];
  float2 l1 = *(const float2*)&LW3[(64 + lane) * 2];
  float hc0 = wsum(xn0 * w0.x + xn1 * w1.x);
  float hc1 = wsum(xn0 * w0.y + xn1 * w1.y);
  float lc0 = wsum(xn0 * l0.x + xn1 * l1.x);
  float lc1 = wsum(xn0 * l0.y + xn1 * l1.y);
  if (lane == 0) {
    h3[2 * n] = hc0; h3[2 * n + 1] = hc1;
    lin3[2 * n] = lc0; lin3[2 * n + 1] = lc1;
    es3[n] = hc0 * as3[0] + hc1 * as3[1];
    ed3[n] = hc0 * ad3[0] + hc1 * ad3[1];
  }
}

// ---------- layer 3 edge aggregation + final output ----------
__global__ __launch_bounds__(256) void k_agg3(
    const int* __restrict__ rowptr, const int* __restrict__ col,
    const float* __restrict__ es, const float* __restrict__ ed,
    const float* __restrict__ h3, const float* __restrict__ lin3,
    const float* __restrict__ lb3, const float* __restrict__ gb3,
    float* __restrict__ out, int N) {
  int lane = threadIdx.x & 63;
  int d = blockIdx.x * 4 + (threadIdx.x >> 6);
  if (d >= N) return;
  int start = rowptr[d], end = rowptr[d + 1];
  float edd = ed[d];
  float ps = 0.f, a0 = 0.f, a1 = 0.f;
  for (int i = start + lane; i < end; i += 64) {
    int s = col[i];
    float e = es[s] + edd; e = e > 0.f ? e : LEAKY * e;
    float p = __expf(e);
    float2 hv = *(const float2*)&h3[2 * s];
    ps += p; a0 += p * hv.x; a1 += p * hv.y;
  }
  ps = wsum(ps); a0 = wsum(a0); a1 = wsum(a1);
  if (lane < 2) {
    float a = (lane == 0 ? a0 : a1) / ps;
    float v = lin3[2 * d + lane] + lb3[lane] + a + gb3[lane];
    out[2 * d + lane] = v > 0.f ? v : 0.f;
  }
}

extern "C" void kernel_launch(void* const* d_in, const int* in_sizes, int n_in,
                              void* d_out, int out_size, void* d_ws, size_t ws_size,
                              hipStream_t stream) {
  const float* x   = (const float*)d_in[0];
  const void*  ei  = d_in[1];
  const float* W1  = (const float*)d_in[2];
  const float* as1 = (const float*)d_in[3];
  const float* ad1 = (const float*)d_in[4];
  const float* gb1 = (const float*)d_in[5];
  const float* lw1 = (const float*)d_in[6];
  const float* lb1 = (const float*)d_in[7];
  const float* bg1 = (const float*)d_in[8];
  const float* bb1 = (const float*)d_in[9];
  const float* W2  = (const float*)d_in[10];
  const float* as2 = (const float*)d_in[11];
  const float* ad2 = (const float*)d_in[12];
  const float* gb2 = (const float*)d_in[13];
  const float* lw2 = (const float*)d_in[14];
  const float* lb2 = (const float*)d_in[15];
  const float* bg2 = (const float*)d_in[16];
  const float* bb2 = (const float*)d_in[17];
  const float* W3  = (const float*)d_in[18];
  const float* as3 = (const float*)d_in[19];
  const float* ad3 = (const float*)d_in[20];
  const float* gb3 = (const float*)d_in[21];
  const float* lw3 = (const float*)d_in[22];
  const float* lb3 = (const float*)d_in[23];
  const float* bg3 = (const float*)d_in[24];
  const float* bb3 = (const float*)d_in[25];
  float* out = (float*)d_out;

  int N = in_sizes[0] / 128;
  int E = in_sizes[1] / 2;
  int M = E + N;
  int nblk = (M + BCHUNK - 1) / BCHUNK;

  char* wsp = (char*)d_ws;
  size_t off = 0;
  auto alloc = [&](size_t bytes) -> void* {
    void* p = wsp + off;
    off = (off + bytes + 255) & ~(size_t)255;
    return p;
  };
  int* rowptr   = (int*)alloc(((size_t)N + 1) * 4);
  int* col      = (int*)alloc((size_t)M * 4);
  int* cnt      = (int*)alloc((size_t)N * 4);
  int* cur      = (int*)alloc((size_t)N * 4);
  float* st1    = (float*)alloc(8 * 256 * 4);
  float* st2    = (float*)alloc(8 * 256 * 4);
  float* st3    = (float*)alloc(8 * 256 * 4);
  unsigned short* Bp1 = (unsigned short*)alloc(4608 * 16);  // 9 tiles
  unsigned short* Bp2 = (unsigned short*)alloc(4608 * 16);
  unsigned* hbp  = (unsigned*)alloc((size_t)N * 64 * 4);
  unsigned* linp = (unsigned*)alloc((size_t)N * 64 * 4);
  unsigned* x2p  = (unsigned*)alloc((size_t)N * 64 * 4);
  float* es    = (float*)alloc((size_t)N * 2 * 4);
  float* edb   = (float*)alloc((size_t)N * 2 * 4);
  float* h3    = (float*)alloc((size_t)N * 2 * 4);
  float* lin3  = (float*)alloc((size_t)N * 2 * 4);
  float* es3   = (float*)alloc((size_t)N * 4);
  float* ed3   = (float*)alloc((size_t)N * 4);
  (void)ws_size; (void)n_in; (void)out_size;

  hipMemsetAsync(st1, 0, 3 * 8 * 256 * 4, stream);  // st1,st2,st3 contiguous
  hipMemsetAsync(cnt, 0, (size_t)N * 4, stream);

  int gnode = (N + 3) / 4;
  int gmm = (N + 31) / 32;

  // K1: weight prep + layer-1 BN stats + per-dst histogram (merged)
  k_prepA<<<1058 + nblk, 256, 0, stream>>>(W1, lw1, W2, lw2, as1, ad1, as2, ad2,
                                           x, N, Bp1, Bp2, st1,
                                           ei, E, M, nblk, cnt);
  k_binScan<<<1, 1024, 0, stream>>>(cnt, N, M, rowptr, cur);
  // K3: layer-1 matmul + direct-to-col scatter (merged) -- binD eliminated
  k_mmC<<<gmm + nblk, 256, 0, stream>>>(x, 0, st1, bg1, bb1, Bp1, hbp, linp, es, edb, N,
                                        gmm, ei, E, M, nblk, cur, col);

  // ---- layer 1 aggregation ----
  k_agg<<<gnode, 256, 0, stream>>>(rowptr, col, es, edb, hbp, linp, lb1, gb1, x2p, N);

  // ---- layer 2 ----
  k_bnstats<<<1024, 128, 0, stream>>>(x2p, N, st2);
  k_mm<<<gmm, 256, 0, stream>>>(x2p, 1, st2, bg2, bb2, Bp2, hbp, linp, es, edb, N);
  k_agg<<<gnode, 256, 0, stream>>>(rowptr, col, es, edb, hbp, linp, lb2, gb2, x2p, N);

  // ---- layer 3 ----
  k_bnstats<<<1024, 128, 0, stream>>>(x2p, N, st3);
  k_l3node<<<gnode, 256, 0, stream>>>(x2p, st3, bg3, bb3, W3, lw3, as3, ad3,
                                      h3, lin3, es3, ed3, N);
  k_agg3<<<gnode, 256, 0, stream>>>(rowptr, col, es3, ed3, h3, lin3, lb3, gb3, out, N);
}

// Round 8
// 394.750 us; speedup vs baseline: 1.5139x; 1.5139x over previous
//
#include <hip/hip_runtime.h>

#define LEAKY 0.2f
#define BN_EPS 1e-5f
#define BCHUNK 8192

typedef __bf16 v8bf __attribute__((ext_vector_type(8)));
typedef float v16f __attribute__((ext_vector_type(16)));
typedef float v2f __attribute__((ext_vector_type(2)));

// ---------- wave helpers (wave64) ----------
__device__ __forceinline__ float wsum(float v) {
#pragma unroll
  for (int o = 32; o > 0; o >>= 1) v += __shfl_xor(v, o, 64);
  return v;
}

// packed-bf16: dword holds feat2j (low16) and feat2j+1 (high16)
__device__ __forceinline__ float blo(unsigned u) { return __uint_as_float(u << 16); }
__device__ __forceinline__ float bhi(unsigned u) { return __uint_as_float(u & 0xffff0000u); }
__device__ __forceinline__ v2f bpair(unsigned u) {
  v2f r; r.x = __uint_as_float(u << 16); r.y = __uint_as_float(u & 0xffff0000u); return r;
}
__device__ __forceinline__ unsigned pack_bf16(float a, float b) {
  unsigned ua = __float_as_uint(a), ub = __float_as_uint(b);
  ua = (ua + 0x7fffu + ((ua >> 16) & 1u)) >> 16;
  ub = (ub + 0x7fffu + ((ub >> 16) & 1u)) >> 16;
  return ua | (ub << 16);
}
__device__ __forceinline__ unsigned short bf16of(float a) {
  unsigned ua = __float_as_uint(a);
  return (unsigned short)((ua + 0x7fffu + ((ua >> 16) & 1u)) >> 16);
}

// D = c + a.lo*b.lo + a.hi*b.hi  (bf16 pairs, f32 accumulate)
__device__ __forceinline__ float dot2bf(unsigned a, unsigned b, float c) {
  asm("v_dot2_f32_bf16 %0, %1, %2, %0" : "+v"(c) : "v"(a), "v"(b));
  return c;
}
// (lo16(u1), lo16(u2)) packed into one dword
__device__ __forceinline__ unsigned permlo(unsigned u1, unsigned u2) {
  return __builtin_amdgcn_perm(u2, u1, 0x05040100u);
}
// (hi16(u1), hi16(u2)) packed into one dword
__device__ __forceinline__ unsigned permhi(unsigned u1, unsigned u2) {
  return __builtin_amdgcn_perm(u2, u1, 0x07060302u);
}

// edge_index may be int64 (reference dtype) or int32 (JAX x64 disabled).
__device__ __forceinline__ int edge_at(const void* ei, int is64, long long i) {
  return is64 ? (int)((const long long*)ei)[i] : ((const int*)ei)[i];
}

// =================== device bodies (shared by merged kernels) ===================

// binA: per-chunk bucket histogram (bucket = dst>>7). lds: >=1025 ints.
__device__ __forceinline__ void binA_body(int blk, const void* ei, int N, int E, int M,
                                          int nb, int nblk, int* counts, int* lds) {
  int* hist = lds;
  int* sflag = lds + 1024;
  int tid = threadIdx.x;
  if (tid < 64) {
    const long long* p = (const long long*)ei;
    long long v = p[tid];
    int bad = (v < 0 || v >= (long long)N) ? 1 : 0;
    unsigned long long mres = __ballot(bad);
    if (tid == 0) *sflag = (mres == 0ull) ? 1 : 0;
  }
  for (int j = tid; j < nb; j += 256) hist[j] = 0;
  __syncthreads();
  int is64 = *sflag;
  long long base = (long long)blk * BCHUNK;
  int cnt = (int)min((long long)BCHUNK, (long long)M - base);
  for (int i = tid; i < cnt; i += 256) {
    long long g = base + i;
    int d = (g < E) ? edge_at(ei, is64, (long long)E + g) : (int)(g - E);
    atomicAdd(&hist[d >> 7], 1);
  }
  __syncthreads();
  for (int j = tid; j < nb; j += 256) counts[(size_t)j * nblk + blk] = hist[j];
}

// binC: scatter packed (src<<7 | dst&127) into bucket-partitioned tmp.
// cursor = bucketBase[j] + within-bucket prefix (from hierarchical scan).
__device__ __forceinline__ void binC_body(int blk, const void* ei, int N, int E, int M,
                                          int nb, int nblk, const int* counts,
                                          const int* bucketBase,
                                          unsigned* tmp, int* lds) {
  int* cur = lds;
  int* sflag = lds + 1024;
  int tid = threadIdx.x;
  if (tid < 64) {
    const long long* p = (const long long*)ei;
    long long v = p[tid];
    int bad = (v < 0 || v >= (long long)N) ? 1 : 0;
    unsigned long long mres = __ballot(bad);
    if (tid == 0) *sflag = (mres == 0ull) ? 1 : 0;
  }
  for (int j = tid; j < nb; j += 256)
    cur[j] = bucketBase[j] + counts[(size_t)j * nblk + blk];
  __syncthreads();
  int is64 = *sflag;
  long long base = (long long)blk * BCHUNK;
  int cnt = (int)min((long long)BCHUNK, (long long)M - base);
  for (int i = tid; i < cnt; i += 256) {
    long long g = base + i;
    int s, d;
    if (g < E) { s = edge_at(ei, is64, g); d = edge_at(ei, is64, (long long)E + g); }
    else       { s = d = (int)(g - E); }
    int pos = atomicAdd(&cur[d >> 7], 1);
    tmp[pos] = ((unsigned)s << 7) | (unsigned)(d & 127);
  }
}

#define MM_SMEM (32 * 136 * 2 + 128 * 4 + 128 * 4)  // Al + scl + sht = 9728 B

// MFMA matmul + es/ed via 9th B-tile (wave 0). smem: MM_SMEM bytes, 16-aligned.
__device__ __forceinline__ void mm_body(int blk, const void* xin, int packed,
    const float* stats, const float* gamma, const float* beta,
    const unsigned short* Bp, unsigned* hb, unsigned* linp,
    float* es, float* ed, int N, char* smem) {
  unsigned short* Al = (unsigned short*)smem;                  // 32*136
  float* scl_s = (float*)(smem + 8704);
  float* sht_s = (float*)(smem + 8704 + 512);
  int tid = threadIdx.x;
  int lane = tid & 63;
  int w = tid >> 6;
  int rowBase = blk * 32;

  if (tid < 128) {
    float s = 0.f, s2 = 0.f;
#pragma unroll
    for (int r = 0; r < 8; ++r) {
      s += stats[r * 256 + tid];
      s2 += stats[r * 256 + 128 + tid];
    }
    float inv_n = 1.0f / (float)N;
    float mu = s * inv_n;
    float var = s2 * inv_n - mu * mu;
    float rs = rsqrtf(var + BN_EPS);
    float sc = gamma[tid] * rs;
    scl_s[tid] = sc;
    sht_s[tid] = beta[tid] - mu * sc;
  }

  v8bf bfrag[2][8];
#pragma unroll
  for (int t = 0; t < 2; ++t)
#pragma unroll
    for (int s = 0; s < 8; ++s) {
      int fi = ((2 * w + t) * 8 + s) * 64 + lane;
      bfrag[t][s] = *(const v8bf*)&Bp[(size_t)fi * 8];
    }
  __syncthreads();

  if (!packed) {
    const float* x = (const float*)xin;
    for (int q = tid; q < 32 * 32; q += 256) {
      int r = q >> 5, k4 = (q & 31) * 4;
      int row = rowBase + r;
      float4 v = make_float4(0.f, 0.f, 0.f, 0.f);
      if (row < N) v = *(const float4*)&x[(size_t)row * 128 + k4];
      unsigned p0 = pack_bf16(v.x * scl_s[k4] + sht_s[k4], v.y * scl_s[k4 + 1] + sht_s[k4 + 1]);
      unsigned p1 = pack_bf16(v.z * scl_s[k4 + 2] + sht_s[k4 + 2], v.w * scl_s[k4 + 3] + sht_s[k4 + 3]);
      *(uint2*)&Al[r * 136 + k4] = make_uint2(p0, p1);
    }
  } else {
    const unsigned* xp = (const unsigned*)xin;
    for (int q = tid; q < 32 * 16; q += 256) {
      int r = q >> 4, g = q & 15;
      int row = rowBase + r;
      uint4 u = make_uint4(0u, 0u, 0u, 0u);
      if (row < N) u = *(const uint4*)&xp[(size_t)row * 64 + g * 4];
      int f = g * 8;
      uint4 o;
      o.x = pack_bf16(blo(u.x) * scl_s[f] + sht_s[f], bhi(u.x) * scl_s[f + 1] + sht_s[f + 1]);
      o.y = pack_bf16(blo(u.y) * scl_s[f + 2] + sht_s[f + 2], bhi(u.y) * scl_s[f + 3] + sht_s[f + 3]);
      o.z = pack_bf16(blo(u.z) * scl_s[f + 4] + sht_s[f + 4], bhi(u.z) * scl_s[f + 5] + sht_s[f + 5]);
      o.w = pack_bf16(blo(u.w) * scl_s[f + 6] + sht_s[f + 6], bhi(u.w) * scl_s[f + 7] + sht_s[f + 7]);
      *(uint4*)&Al[r * 136 + f] = o;
    }
  }
  __syncthreads();

  int m = lane & 31, half = lane >> 5;
  v8bf afrag[8];
#pragma unroll
  for (int s = 0; s < 8; ++s)
    afrag[s] = *(const v8bf*)&Al[m * 136 + s * 16 + half * 8];

  v16f acc0 = {}, acc1 = {};
#pragma unroll
  for (int s = 0; s < 8; ++s) {
    acc0 = __builtin_amdgcn_mfma_f32_32x32x16_bf16(afrag[s], bfrag[0][s], acc0, 0, 0, 0);
    acc1 = __builtin_amdgcn_mfma_f32_32x32x16_bf16(afrag[s], bfrag[1][s], acc1, 0, 0, 0);
  }

  v16f acc2 = {};
  if (w == 0) {
#pragma unroll
    for (int s = 0; s < 8; ++s) {
      v8bf besf = *(const v8bf*)&Bp[(size_t)((64 + s) * 64 + lane) * 8];
      acc2 = __builtin_amdgcn_mfma_f32_32x32x16_bf16(afrag[s], besf, acc2, 0, 0, 0);
    }
  }

  int mlo = half * 4;
  int t0 = 2 * w, t1 = 2 * w + 1;
#pragma unroll
  for (int r = 0; r < 16; ++r) {
    int row = (r & 3) + 8 * (r >> 2) + mlo;
    int node = rowBase + row;
    float a0 = acc0[r], a1 = acc1[r];
    float b0 = __shfl_xor(a0, 1, 64);
    float b1 = __shfl_xor(a1, 1, 64);
    if (node < N && !(lane & 1)) {
      if (t0 < 4) {
        hb[(size_t)node * 64 + (t0 * 16 + (m >> 1))] = pack_bf16(a0, b0);
        hb[(size_t)node * 64 + (t1 * 16 + (m >> 1))] = pack_bf16(a1, b1);
      } else {
        linp[(size_t)node * 64 + ((t0 - 4) * 16 + (m >> 1))] = pack_bf16(a0, b0);
        linp[(size_t)node * 64 + ((t1 - 4) * 16 + (m >> 1))] = pack_bf16(a1, b1);
      }
    }
    if (w == 0 && m < 4 && node < N) {
      float v = acc2[r];
      if (m < 2) es[2 * node + (m & 1)] = v;
      else       ed[2 * node + (m & 1)] = v;
    }
  }
}

// =================== kernels ===================

// K1: prep (Bp tiles 0-8, Wesed->tile8, layer-1 BN stats) UNION binA.
// blocks [0,34): weight prep; [34,1058): stats; [1058, 1058+nblk): binA.
__global__ __launch_bounds__(256) void k_prepA(
    const float* __restrict__ W1, const float* __restrict__ LW1,
    const float* __restrict__ W2, const float* __restrict__ LW2,
    const float* __restrict__ as1, const float* __restrict__ ad1,
    const float* __restrict__ as2, const float* __restrict__ ad2,
    const float* __restrict__ x, int N,
    unsigned short* __restrict__ Bp1, unsigned short* __restrict__ Bp2,
    float* __restrict__ stats1,
    const void* ei, int E, int M, int nb, int nblk, int* counts) {
  __shared__ __align__(16) int lds[1025];
  int blk = blockIdx.x;
  int tid = threadIdx.x;
  if (blk >= 1058) { binA_body(blk - 1058, ei, N, E, M, nb, nblk, counts, lds); return; }
  if (blk >= 34) {
    int b = blk - 34;  // 0..1023
    int f = tid & 127;
    int half = tid >> 7;
    float s = 0.f, s2 = 0.f;
    for (int r = b + half * 1024; r < N; r += 2048) {
      float v = x[(size_t)r * 128 + f];
      s += v; s2 += v * v;
    }
    float* rep = stats1 + (size_t)(b & 7) * 256;
    atomicAdd(&rep[f], s);
    atomicAdd(&rep[128 + f], s2);
    return;
  }
  if (blk >= 32) {
    // tile 8: es/ed columns in B-fragment order
    float (*wes)[4] = (float(*)[4])lds;  // 128x4 floats = 2 KB
    const float* W = (blk == 32) ? W1 : W2;
    const float* as_ = (blk == 32) ? as1 : as2;
    const float* ad_ = (blk == 32) ? ad1 : ad2;
    unsigned short* Bp = (blk == 32) ? Bp1 : Bp2;
#pragma unroll
    for (int it = 0; it < 2; ++it) {
      int k = tid & 127;
      int c = (tid >> 7) + 2 * it;
      const float* a = (c < 2) ? as_ : ad_;
      int hb2 = (c & 1) * 64;
      float sum = 0.f;
      for (int f = 0; f < 64; ++f) sum += W[k * 128 + hb2 + f] * a[hb2 + f];
      wes[k][c] = sum;
    }
    __syncthreads();
    for (int fr = tid; fr < 512; fr += 256) {
      int lane = fr & 63, s = fr >> 6;
      int n = lane & 31;
      int k0 = s * 16 + (lane >> 5) * 8;
      unsigned short tb[8];
#pragma unroll
      for (int j = 0; j < 8; ++j)
        tb[j] = bf16of((n < 4) ? wes[k0 + j][n] : 0.f);
      uint4 pk;
      pk.x = (unsigned)tb[0] | ((unsigned)tb[1] << 16);
      pk.y = (unsigned)tb[2] | ((unsigned)tb[3] << 16);
      pk.z = (unsigned)tb[4] | ((unsigned)tb[5] << 16);
      pk.w = (unsigned)tb[6] | ((unsigned)tb[7] << 16);
      int fi = (64 + s) * 64 + lane;
      *(uint4*)&Bp[(size_t)fi * 8] = pk;
    }
    return;
  }
  const float* W  = (blk < 16) ? W1 : W2;
  const float* LW = (blk < 16) ? LW1 : LW2;
  unsigned short* Bp = (blk < 16) ? Bp1 : Bp2;
  int fi = (blk & 15) * 256 + tid;  // 4096 frags (tiles 0-7)
  int lane = fi & 63, s = (fi >> 6) & 7, t = fi >> 9;
  int n = t * 32 + (lane & 31);
  int k0 = s * 16 + (lane >> 5) * 8;
  unsigned short tb[8];
#pragma unroll
  for (int j = 0; j < 8; ++j) {
    int k = k0 + j;
    float v = (n < 128) ? W[k * 128 + n] : LW[k * 128 + (n - 128)];
    tb[j] = bf16of(v);
  }
  uint4 pk;
  pk.x = (unsigned)tb[0] | ((unsigned)tb[1] << 16);
  pk.y = (unsigned)tb[2] | ((unsigned)tb[3] << 16);
  pk.z = (unsigned)tb[4] | ((unsigned)tb[5] << 16);
  pk.w = (unsigned)tb[6] | ((unsigned)tb[7] << 16);
  *(uint4*)&Bp[(size_t)fi * 8] = pk;
}

// scanA: per-bucket (row) exclusive scan of its nblk chunk-counts, in-place;
// writes rowTotal[j]. 391 blocks run in parallel -- no serial 79K scan.
__global__ __launch_bounds__(256) void k_scanA(int* __restrict__ counts, int nblk,
                                               int* __restrict__ rowTotal) {
  __shared__ int part[256];
  int tid = threadIdx.x;
  int j = blockIdx.x;
  int* row = counts + (size_t)j * nblk;
  int per = (nblk + 255) / 256;
  int lo = tid * per;
  int hi = lo + per; if (hi > nblk) hi = nblk;
  int s = 0;
  for (int i = lo; i < hi; ++i) s += row[i];
  part[tid] = s;
  __syncthreads();
  for (int off = 1; off < 256; off <<= 1) {
    int add = (tid >= off) ? part[tid - off] : 0;
    __syncthreads();
    part[tid] += add;
    __syncthreads();
  }
  int run = (tid == 0) ? 0 : part[tid - 1];
  for (int i = lo; i < hi; ++i) {
    int c = row[i];
    row[i] = run;
    run += c;
  }
  if (tid == 0) rowTotal[j] = part[255];
}

// scanB: exclusive scan of nb bucket totals -> bucketBase; bucketBase[nb]=M.
__global__ __launch_bounds__(512) void k_scanB(const int* __restrict__ rowTotal, int nb,
                                               int M, int* __restrict__ bucketBase) {
  __shared__ int part[512];
  int tid = threadIdx.x;
  int per = (nb + 511) / 512;
  int lo = tid * per;
  int hi = lo + per; if (hi > nb) hi = nb;
  int s = 0;
  for (int i = lo; i < hi; ++i) s += rowTotal[i];
  part[tid] = s;
  __syncthreads();
  for (int off = 1; off < 512; off <<= 1) {
    int add = (tid >= off) ? part[tid - off] : 0;
    __syncthreads();
    part[tid] += add;
    __syncthreads();
  }
  int run = (tid == 0) ? 0 : part[tid - 1];
  for (int i = lo; i < hi; ++i) {
    bucketBase[i] = run;
    run += rowTotal[i];
  }
  if (tid == 0) bucketBase[nb] = M;
}

// K3: layer-1 MFMA matmul UNION binC. blocks [0,gmm): mm; [gmm, gmm+nblk): binC.
__global__ __launch_bounds__(256) void k_mmC(
    const void* __restrict__ xin, int packed,
    const float* __restrict__ stats, const float* __restrict__ gamma, const float* __restrict__ beta,
    const unsigned short* __restrict__ Bp,
    unsigned* __restrict__ hb, unsigned* __restrict__ linp,
    float* __restrict__ es, float* __restrict__ ed, int N, int gmm,
    const void* ei, int E, int M, int nb, int nblk, const int* counts,
    const int* bucketBase, unsigned* tmp) {
  __shared__ __align__(16) char smem[MM_SMEM];
  int blk = blockIdx.x;
  if (blk < gmm) {
    mm_body(blk, xin, packed, stats, gamma, beta, Bp, hb, linp, es, ed, N, smem);
  } else {
    binC_body(blk - gmm, ei, N, E, M, nb, nblk, counts, bucketBase, tmp, (int*)smem);
  }
}

// standalone mm (layer 2)
__global__ __launch_bounds__(256) void k_mm(
    const void* __restrict__ xin, int packed,
    const float* __restrict__ stats, const float* __restrict__ gamma, const float* __restrict__ beta,
    const unsigned short* __restrict__ Bp,
    unsigned* __restrict__ hb, unsigned* __restrict__ linp,
    float* __restrict__ es, float* __restrict__ ed, int N) {
  __shared__ __align__(16) char smem[MM_SMEM];
  mm_body(blockIdx.x, xin, packed, stats, gamma, beta, Bp, hb, linp, es, ed, N, smem);
}

// binD: per-bucket (128 dsts) counting sort -> rowptr + col.
__global__ __launch_bounds__(256) void k_binD(const unsigned* __restrict__ tmp,
                                              const int* __restrict__ bucketBase,
                                              int nb, int M, int N,
                                              int* __restrict__ rowptr, int* __restrict__ col) {
  __shared__ int scn[128];
  __shared__ int cur[128];
  int tid = threadIdx.x;
  int j = blockIdx.x;
  int base = bucketBase[j];
  int endv = bucketBase[j + 1];
  int bc = endv - base;
  if (tid < 128) scn[tid] = 0;
  __syncthreads();
  for (int i = tid; i < bc; i += 256) atomicAdd(&scn[tmp[base + i] & 127], 1);
  __syncthreads();
  int v = (tid < 128) ? scn[tid] : 0;
  __syncthreads();
  for (int off = 1; off < 128; off <<= 1) {
    int add = (tid >= off && tid < 128) ? scn[tid - off] : 0;
    __syncthreads();
    if (tid < 128) scn[tid] += add;
    __syncthreads();
  }
  if (tid < 128) {
    int excl = scn[tid] - v;
    int d = (j << 7) + tid;
    if (d < N) rowptr[d] = base + excl;
    cur[tid] = base + excl;
  }
  __syncthreads();
  for (int i = tid; i < bc; i += 256) {
    unsigned w = tmp[base + i];
    int pos = atomicAdd(&cur[w & 127], 1);
    col[pos] = (int)(w >> 7);
  }
  if (j == nb - 1 && tid == 0) rowptr[N] = M;
}

// ---------- BatchNorm stats for packed-bf16 input (layers 2/3) ----------
__global__ __launch_bounds__(128) void k_bnstats(const unsigned* __restrict__ xp,
                                                 int N, float* sums) {
  int f = threadIdx.x;
  int q = f >> 1, hi = f & 1;
  float s = 0.f, s2 = 0.f;
  for (int r = blockIdx.x; r < N; r += gridDim.x) {
    unsigned u = xp[(size_t)r * 64 + q];
    float v = hi ? bhi(u) : blo(u);
    s += v; s2 += v * v;
  }
  float* rep = sums + (size_t)(blockIdx.x & 7) * 256;
  atomicAdd(&rep[f], s);
  atomicAdd(&rep[128 + f], s2);
}

// ---------- single-pass edge aggregation + combine; one wave per dst ----------
// Phase-split + perm/dot2; 16 edges/iter main loop (4 gathers in flight).
__global__ __launch_bounds__(256) void k_agg(
    const int* __restrict__ rowptr, const int* __restrict__ col,
    const float* __restrict__ es, const float* __restrict__ ed,
    const unsigned* __restrict__ hb, const unsigned* __restrict__ linp,
    const float* __restrict__ lb, const float* __restrict__ gb,
    unsigned* __restrict__ xoutp, int N) {
  __shared__ unsigned short phb[4][2][64];  // p (bf16) per head, per wave
  __shared__ unsigned obuf[4][64];          // hb dword offsets, per wave
  int lane = threadIdx.x & 63;
  int w = threadIdx.x >> 6;
  int d = blockIdx.x * 4 + w;
  if (d >= N) return;
  int start = rowptr[d], end = rowptr[d + 1];
  v2f edv = *(const v2f*)&ed[2 * d];
  int q = lane >> 4;   // edge-pair group 0..3
  int m = lane & 15;   // feats 8m..8m+7
  int head_hi = m >= 8;
  v2f zero = {0.f, 0.f};
  v2f lk = {LEAKY, LEAKY};

  v2f acc[4] = {zero, zero, zero, zero};
  v2f spv = zero;                       // per-lane softmax denom partial (both heads)
  unsigned short* ph = &phb[w][0][0];
  unsigned* oo = obuf[w];
  int hoff = head_hi ? 64 : 0;

  for (int base = start; base < end; base += 64) {
    int cnt = end - base; if (cnt > 64) cnt = 64;
    // ---- phase 1: p for up to 64 edges, one per lane (exp computed once/edge) ----
    {
      int valid = lane < cnt;
      int s = col[valid ? base + lane : base];
      v2f ev = *(const v2f*)&es[2 * s];
      v2f e = ev + edv;
      v2f le = __builtin_elementwise_max(e, zero) + lk * __builtin_elementwise_min(e, zero);
      v2f p; p.x = __expf(le.x); p.y = __expf(le.y);
      if (!valid) p = zero;             // zero-pad slots [cnt,64): no contribution
      spv += p;
      ph[lane] = bf16of(p.x);
      ph[64 + lane] = bf16of(p.y);
      oo[lane] = (unsigned)s * 64u;     // dword offset of hb row (clamped s is valid)
    }
    // same wave: LDS writes above are ordered before reads below (no barrier needed)
    // ---- phase 2 main: 16 edges/iter, 4 gathers in flight per lane ----
    int i = 0;
    for (; i + 16 <= cnt; i += 16) {
      int e1 = i + 2 * q;               // pair A
      int e2 = i + 8 + 2 * q;           // pair B
      unsigned fpA = *(const unsigned*)&ph[hoff + e1];
      unsigned fpB = *(const unsigned*)&ph[hoff + e2];
      uint2 oA = *(const uint2*)&oo[e1];
      uint2 oB = *(const uint2*)&oo[e2];
      uint4 u1 = *(const uint4*)&hb[(size_t)oA.x + m * 4];
      uint4 u2 = *(const uint4*)&hb[(size_t)oA.y + m * 4];
      uint4 u3 = *(const uint4*)&hb[(size_t)oB.x + m * 4];
      uint4 u4 = *(const uint4*)&hb[(size_t)oB.y + m * 4];
      acc[0].x = dot2bf(fpA, permlo(u1.x, u2.x), acc[0].x);
      acc[0].y = dot2bf(fpA, permhi(u1.x, u2.x), acc[0].y);
      acc[1].x = dot2bf(fpA, permlo(u1.y, u2.y), acc[1].x);
      acc[1].y = dot2bf(fpA, permhi(u1.y, u2.y), acc[1].y);
      acc[2].x = dot2bf(fpA, permlo(u1.z, u2.z), acc[2].x);
      acc[2].y = dot2bf(fpA, permhi(u1.z, u2.z), acc[2].y);
      acc[3].x = dot2bf(fpA, permlo(u1.w, u2.w), acc[3].x);
      acc[3].y = dot2bf(fpA, permhi(u1.w, u2.w), acc[3].y);
      acc[0].x = dot2bf(fpB, permlo(u3.x, u4.x), acc[0].x);
      acc[0].y = dot2bf(fpB, permhi(u3.x, u4.x), acc[0].y);
      acc[1].x = dot2bf(fpB, permlo(u3.y, u4.y), acc[1].x);
      acc[1].y = dot2bf(fpB, permhi(u3.y, u4.y), acc[1].y);
      acc[2].x = dot2bf(fpB, permlo(u3.z, u4.z), acc[2].x);
      acc[2].y = dot2bf(fpB, permhi(u3.z, u4.z), acc[2].y);
      acc[3].x = dot2bf(fpB, permlo(u3.w, u4.w), acc[3].x);
      acc[3].y = dot2bf(fpB, permhi(u3.w, u4.w), acc[3].y);
    }
    // ---- phase 2 remainder: 8 edges/iter (p zero-padded beyond cnt) ----
    for (; i < cnt; i += 8) {
      int e1 = i + 2 * q;               // e1 <= 63 always (i <= 56)
      unsigned fp = *(const unsigned*)&ph[hoff + e1];
      uint2 ofs = *(const uint2*)&oo[e1];
      uint4 u1 = *(const uint4*)&hb[(size_t)ofs.x + m * 4];
      uint4 u2 = *(const uint4*)&hb[(size_t)ofs.y + m * 4];
      acc[0].x = dot2bf(fp, permlo(u1.x, u2.x), acc[0].x);
      acc[0].y = dot2bf(fp, permhi(u1.x, u2.x), acc[0].y);
      acc[1].x = dot2bf(fp, permlo(u1.y, u2.y), acc[1].x);
      acc[1].y = dot2bf(fp, permhi(u1.y, u2.y), acc[1].y);
      acc[2].x = dot2bf(fp, permlo(u1.z, u2.z), acc[2].x);
      acc[2].y = dot2bf(fp, permhi(u1.z, u2.z), acc[2].y);
      acc[3].x = dot2bf(fp, permlo(u1.w, u2.w), acc[3].x);
      acc[3].y = dot2bf(fp, permhi(u1.w, u2.w), acc[3].y);
    }
  }
  // reduce acc across quarters
#pragma unroll
  for (int k = 0; k < 4; ++k) {
    acc[k].x += __shfl_xor(acc[k].x, 16, 64);
    acc[k].x += __shfl_xor(acc[k].x, 32, 64);
    acc[k].y += __shfl_xor(acc[k].y, 16, 64);
    acc[k].y += __shfl_xor(acc[k].y, 32, 64);
  }
  // reduce softmax denom across all 64 lanes (one edge per lane in phase 1)
#pragma unroll
  for (int o = 1; o < 64; o <<= 1) {
    spv.x += __shfl_xor(spv.x, o, 64);
    spv.y += __shfl_xor(spv.y, o, 64);
  }

  if (q == 0) {
    float inv = 1.0f / (head_hi ? spv.y : spv.x);
    uint4 lv = *(const uint4*)&linp[(size_t)d * 64 + m * 4];
    int f8 = 8 * m;
    float4 lb0 = *(const float4*)&lb[f8], lb1 = *(const float4*)&lb[f8 + 4];
    float4 gb0 = *(const float4*)&gb[f8], gb1 = *(const float4*)&gb[f8 + 4];
    float v0 = blo(lv.x) + lb0.x + acc[0].x * inv + gb0.x;
    float v1 = bhi(lv.x) + lb0.y + acc[0].y * inv + gb0.y;
    float v2 = blo(lv.y) + lb0.z + acc[1].x * inv + gb0.z;
    float v3 = bhi(lv.y) + lb0.w + acc[1].y * inv + gb0.w;
    float v4 = blo(lv.z) + lb1.x + acc[2].x * inv + gb1.x;
    float v5 = bhi(lv.z) + lb1.y + acc[2].y * inv + gb1.y;
    float v6 = blo(lv.w) + lb1.z + acc[3].x * inv + gb1.z;
    float v7 = bhi(lv.w) + lb1.w + acc[3].y * inv + gb1.w;
    v0 = v0 > 0.f ? v0 : 0.f; v1 = v1 > 0.f ? v1 : 0.f;
    v2 = v2 > 0.f ? v2 : 0.f; v3 = v3 > 0.f ? v3 : 0.f;
    v4 = v4 > 0.f ? v4 : 0.f; v5 = v5 > 0.f ? v5 : 0.f;
    v6 = v6 > 0.f ? v6 : 0.f; v7 = v7 > 0.f ? v7 : 0.f;
    uint4 o;
    o.x = pack_bf16(v0, v1); o.y = pack_bf16(v2, v3);
    o.z = pack_bf16(v4, v5); o.w = pack_bf16(v6, v7);
    *(uint4*)&xoutp[(size_t)d * 64 + m * 4] = o;
  }
}

// ---------- layer 3: BN(inline, 8-replica stats) + tiny matmul + es/ed ----------
__global__ __launch_bounds__(256) void k_l3node(
    const unsigned* __restrict__ xp,
    const float* __restrict__ stats, const float* __restrict__ gamma, const float* __restrict__ beta,
    const float* __restrict__ W3, const float* __restrict__ LW3,
    const float* __restrict__ as3, const float* __restrict__ ad3,
    float* h3, float* lin3, float* es3, float* ed3, int N) {
  int lane = threadIdx.x & 63;
  int n = blockIdx.x * 4 + (threadIdx.x >> 6);
  if (n >= N) return;
  float inv_n = 1.0f / (float)N;
  int f0 = lane, f1 = 64 + lane;
  float su0 = 0.f, sq0 = 0.f, su1 = 0.f, sq1 = 0.f;
#pragma unroll
  for (int r = 0; r < 8; ++r) {
    su0 += stats[r * 256 + f0];  sq0 += stats[r * 256 + 128 + f0];
    su1 += stats[r * 256 + f1];  sq1 += stats[r * 256 + 128 + f1];
  }
  float mu0 = su0 * inv_n;
  float var0 = sq0 * inv_n - mu0 * mu0;
  float rs0 = rsqrtf(var0 + BN_EPS);
  float sc0 = gamma[f0] * rs0, sh0 = beta[f0] - mu0 * sc0;
  float mu1 = su1 * inv_n;
  float var1 = sq1 * inv_n - mu1 * mu1;
  float rs1 = rsqrtf(var1 + BN_EPS);
  float sc1 = gamma[f1] * rs1, sh1 = beta[f1] - mu1 * sc1;

  unsigned ua = xp[(size_t)n * 64 + (lane >> 1)];
  unsigned ub = xp[(size_t)n * 64 + 32 + (lane >> 1)];
  float xv0 = (lane & 1) ? bhi(ua) : blo(ua);
  float xv1 = (lane & 1) ? bhi(ub) : blo(ub);
  float xn0 = xv0 * sc0 + sh0;
  float xn1 = xv1 * sc1 + sh1;

  float2 w0 = *(const float2*)&W3[lane * 2];
  float2 w1 = *(const float2*)&W3[(64 + lane) * 2];
  float2 l0 = *(const float2*)&LW3[lane * 2];
  float2 l1 = *(const float2*)&LW3[(64 + lane) * 2];
  float hc0 = wsum(xn0 * w0.x + xn1 * w1.x);
  float hc1 = wsum(xn0 * w0.y + xn1 * w1.y);
  float lc0 = wsum(xn0 * l0.x + xn1 * l1.x);
  float lc1 = wsum(xn0 * l0.y + xn1 * l1.y);
  if (lane == 0) {
    h3[2 * n] = hc0; h3[2 * n + 1] = hc1;
    lin3[2 * n] = lc0; lin3[2 * n + 1] = lc1;
    es3[n] = hc0 * as3[0] + hc1 * as3[1];
    ed3[n] = hc0 * ad3[0] + hc1 * ad3[1];
  }
}

// ---------- layer 3 edge aggregation + final output ----------
__global__ __launch_bounds__(256) void k_agg3(
    const int* __restrict__ rowptr, const int* __restrict__ col,
    const float* __restrict__ es, const float* __restrict__ ed,
    const float* __restrict__ h3, const float* __restrict__ lin3,
    const float* __restrict__ lb3, const float* __restrict__ gb3,
    float* __restrict__ out, int N) {
  int lane = threadIdx.x & 63;
  int d = blockIdx.x * 4 + (threadIdx.x >> 6);
  if (d >= N) return;
  int start = rowptr[d], end = rowptr[d + 1];
  float edd = ed[d];
  float ps = 0.f, a0 = 0.f, a1 = 0.f;
  for (int i = start + lane; i < end; i += 64) {
    int s = col[i];
    float e = es[s] + edd; e = e > 0.f ? e : LEAKY * e;
    float p = __expf(e);
    float2 hv = *(const float2*)&h3[2 * s];
    ps += p; a0 += p * hv.x; a1 += p * hv.y;
  }
  ps = wsum(ps); a0 = wsum(a0); a1 = wsum(a1);
  if (lane < 2) {
    float a = (lane == 0 ? a0 : a1) / ps;
    float v = lin3[2 * d + lane] + lb3[lane] + a + gb3[lane];
    out[2 * d + lane] = v > 0.f ? v : 0.f;
  }
}

extern "C" void kernel_launch(void* const* d_in, const int* in_sizes, int n_in,
                              void* d_out, int out_size, void* d_ws, size_t ws_size,
                              hipStream_t stream) {
  const float* x   = (const float*)d_in[0];
  const void*  ei  = d_in[1];
  const float* W1  = (const float*)d_in[2];
  const float* as1 = (const float*)d_in[3];
  const float* ad1 = (const float*)d_in[4];
  const float* gb1 = (const float*)d_in[5];
  const float* lw1 = (const float*)d_in[6];
  const float* lb1 = (const float*)d_in[7];
  const float* bg1 = (const float*)d_in[8];
  const float* bb1 = (const float*)d_in[9];
  const float* W2  = (const float*)d_in[10];
  const float* as2 = (const float*)d_in[11];
  const float* ad2 = (const float*)d_in[12];
  const float* gb2 = (const float*)d_in[13];
  const float* lw2 = (const float*)d_in[14];
  const float* lb2 = (const float*)d_in[15];
  const float* bg2 = (const float*)d_in[16];
  const float* bb2 = (const float*)d_in[17];
  const float* W3  = (const float*)d_in[18];
  const float* as3 = (const float*)d_in[19];
  const float* ad3 = (const float*)d_in[20];
  const float* gb3 = (const float*)d_in[21];
  const float* lw3 = (const float*)d_in[22];
  const float* lb3 = (const float*)d_in[23];
  const float* bg3 = (const float*)d_in[24];
  const float* bb3 = (const float*)d_in[25];
  float* out = (float*)d_out;

  int N = in_sizes[0] / 128;
  int E = in_sizes[1] / 2;
  int M = E + N;
  int nb = (N + 127) >> 7;            // 128-wide buckets
  int nblk = (M + BCHUNK - 1) / BCHUNK;

  char* wsp = (char*)d_ws;
  size_t off = 0;
  auto alloc = [&](size_t bytes) -> void* {
    void* p = wsp + off;
    off = (off + bytes + 255) & ~(size_t)255;
    return p;
  };
  int* rowptr   = (int*)alloc(((size_t)N + 1) * 4);
  int* col      = (int*)alloc((size_t)M * 4);
  unsigned* tmp = (unsigned*)alloc((size_t)M * 4);
  int* counts   = (int*)alloc(((size_t)nb * nblk + 1) * 4);
  int* rowTotal = (int*)alloc((size_t)nb * 4);
  int* bucketBase = (int*)alloc(((size_t)nb + 1) * 4);
  float* st1    = (float*)alloc(8 * 256 * 4);
  float* st2    = (float*)alloc(8 * 256 * 4);
  float* st3    = (float*)alloc(8 * 256 * 4);
  unsigned short* Bp1 = (unsigned short*)alloc(4608 * 16);  // 9 tiles
  unsigned short* Bp2 = (unsigned short*)alloc(4608 * 16);
  unsigned* hbp  = (unsigned*)alloc((size_t)N * 64 * 4);
  unsigned* linp = (unsigned*)alloc((size_t)N * 64 * 4);
  unsigned* x2p  = (unsigned*)alloc((size_t)N * 64 * 4);
  float* es    = (float*)alloc((size_t)N * 2 * 4);
  float* edb   = (float*)alloc((size_t)N * 2 * 4);
  float* h3    = (float*)alloc((size_t)N * 2 * 4);
  float* lin3  = (float*)alloc((size_t)N * 2 * 4);
  float* es3   = (float*)alloc((size_t)N * 4);
  float* ed3   = (float*)alloc((size_t)N * 4);
  (void)ws_size; (void)n_in; (void)out_size;

  hipMemsetAsync(st1, 0, 3 * 8 * 256 * 4, stream);  // st1,st2,st3 contiguous

  int gnode = (N + 3) / 4;
  int gmm = (N + 31) / 32;

  // K1: weight prep + layer-1 BN stats + binA (merged, independent work)
  k_prepA<<<1058 + nblk, 256, 0, stream>>>(W1, lw1, W2, lw2, as1, ad1, as2, ad2,
                                           x, N, Bp1, Bp2, st1,
                                           ei, E, M, nb, nblk, counts);
  // hierarchical scan: per-bucket parallel scan + tiny bucket-base scan
  k_scanA<<<nb, 256, 0, stream>>>(counts, nblk, rowTotal);
  k_scanB<<<1, 512, 0, stream>>>(rowTotal, nb, M, bucketBase);
  // K3: layer-1 matmul + binC (merged, independent work)
  k_mmC<<<gmm + nblk, 256, 0, stream>>>(x, 0, st1, bg1, bb1, Bp1, hbp, linp, es, edb, N,
                                        gmm, ei, E, M, nb, nblk, counts, bucketBase, tmp);
  k_binD<<<nb, 256, 0, stream>>>(tmp, bucketBase, nb, M, N, rowptr, col);

  // ---- layer 1 aggregation ----
  k_agg<<<gnode, 256, 0, stream>>>(rowptr, col, es, edb, hbp, linp, lb1, gb1, x2p, N);

  // ---- layer 2 ----
  k_bnstats<<<1024, 128, 0, stream>>>(x2p, N, st2);
  k_mm<<<gmm, 256, 0, stream>>>(x2p, 1, st2, bg2, bb2, Bp2, hbp, linp, es, edb, N);
  k_agg<<<gnode, 256, 0, stream>>>(rowptr, col, es, edb, hbp, linp, lb2, gb2, x2p, N);

  // ---- layer 3 ----
  k_bnstats<<<1024, 128, 0, stream>>>(x2p, N, st3);
  k_l3node<<<gnode, 256, 0, stream>>>(x2p, st3, bg3, bb3, W3, lw3, as3, ad3,
                                      h3, lin3, es3, ed3, N);
  k_agg3<<<gnode, 256, 0, stream>>>(rowptr, col, es3, ed3, h3, lin3, lb3, gb3, out, N);
}

// Round 9
// 384.147 us; speedup vs baseline: 1.5557x; 1.0276x over previous
//
#include <hip/hip_runtime.h>

#define LEAKY 0.2f
#define BN_EPS 1e-5f
#define BCHUNK 8192

typedef __bf16 v8bf __attribute__((ext_vector_type(8)));
typedef float v16f __attribute__((ext_vector_type(16)));
typedef float v2f __attribute__((ext_vector_type(2)));

// ---------- wave helpers (wave64) ----------
__device__ __forceinline__ float wsum(float v) {
#pragma unroll
  for (int o = 32; o > 0; o >>= 1) v += __shfl_xor(v, o, 64);
  return v;
}

// packed-bf16: dword holds feat2j (low16) and feat2j+1 (high16)
__device__ __forceinline__ float blo(unsigned u) { return __uint_as_float(u << 16); }
__device__ __forceinline__ float bhi(unsigned u) { return __uint_as_float(u & 0xffff0000u); }
__device__ __forceinline__ v2f bpair(unsigned u) {
  v2f r; r.x = __uint_as_float(u << 16); r.y = __uint_as_float(u & 0xffff0000u); return r;
}
__device__ __forceinline__ unsigned pack_bf16(float a, float b) {
  unsigned ua = __float_as_uint(a), ub = __float_as_uint(b);
  ua = (ua + 0x7fffu + ((ua >> 16) & 1u)) >> 16;
  ub = (ub + 0x7fffu + ((ub >> 16) & 1u)) >> 16;
  return ua | (ub << 16);
}
__device__ __forceinline__ unsigned short bf16of(float a) {
  unsigned ua = __float_as_uint(a);
  return (unsigned short)((ua + 0x7fffu + ((ua >> 16) & 1u)) >> 16);
}

// D = c + a.lo*b.lo + a.hi*b.hi  (bf16 pairs, f32 accumulate)
__device__ __forceinline__ float dot2bf(unsigned a, unsigned b, float c) {
  asm("v_dot2_f32_bf16 %0, %1, %2, %0" : "+v"(c) : "v"(a), "v"(b));
  return c;
}
// (lo16(u1), lo16(u2)) packed into one dword
__device__ __forceinline__ unsigned permlo(unsigned u1, unsigned u2) {
  return __builtin_amdgcn_perm(u2, u1, 0x05040100u);
}
// (hi16(u1), hi16(u2)) packed into one dword
__device__ __forceinline__ unsigned permhi(unsigned u1, unsigned u2) {
  return __builtin_amdgcn_perm(u2, u1, 0x07060302u);
}

// edge_index may be int64 (reference dtype) or int32 (JAX x64 disabled).
__device__ __forceinline__ int edge_at(const void* ei, int is64, long long i) {
  return is64 ? (int)((const long long*)ei)[i] : ((const int*)ei)[i];
}

// =================== device bodies (shared by merged kernels) ===================

// binA: per-chunk bucket histogram (bucket = dst>>7). lds: >=1025 ints.
__device__ __forceinline__ void binA_body(int blk, const void* ei, int N, int E, int M,
                                          int nb, int nblk, int* counts, int* lds) {
  int* hist = lds;
  int* sflag = lds + 1024;
  int tid = threadIdx.x;
  if (tid < 64) {
    const long long* p = (const long long*)ei;
    long long v = p[tid];
    int bad = (v < 0 || v >= (long long)N) ? 1 : 0;
    unsigned long long mres = __ballot(bad);
    if (tid == 0) *sflag = (mres == 0ull) ? 1 : 0;
  }
  for (int j = tid; j < nb; j += 256) hist[j] = 0;
  __syncthreads();
  int is64 = *sflag;
  long long base = (long long)blk * BCHUNK;
  int cnt = (int)min((long long)BCHUNK, (long long)M - base);
  for (int i = tid; i < cnt; i += 256) {
    long long g = base + i;
    int d = (g < E) ? edge_at(ei, is64, (long long)E + g) : (int)(g - E);
    atomicAdd(&hist[d >> 7], 1);
  }
  __syncthreads();
  for (int j = tid; j < nb; j += 256) counts[(size_t)j * nblk + blk] = hist[j];
}

// binC: scatter packed (src<<7 | dst&127) into bucket-partitioned tmp.
// cursor = bucketBase[j] + within-bucket prefix (from hierarchical scan).
__device__ __forceinline__ void binC_body(int blk, const void* ei, int N, int E, int M,
                                          int nb, int nblk, const int* counts,
                                          const int* bucketBase,
                                          unsigned* tmp, int* lds) {
  int* cur = lds;
  int* sflag = lds + 1024;
  int tid = threadIdx.x;
  if (tid < 64) {
    const long long* p = (const long long*)ei;
    long long v = p[tid];
    int bad = (v < 0 || v >= (long long)N) ? 1 : 0;
    unsigned long long mres = __ballot(bad);
    if (tid == 0) *sflag = (mres == 0ull) ? 1 : 0;
  }
  for (int j = tid; j < nb; j += 256)
    cur[j] = bucketBase[j] + counts[(size_t)j * nblk + blk];
  __syncthreads();
  int is64 = *sflag;
  long long base = (long long)blk * BCHUNK;
  int cnt = (int)min((long long)BCHUNK, (long long)M - base);
  for (int i = tid; i < cnt; i += 256) {
    long long g = base + i;
    int s, d;
    if (g < E) { s = edge_at(ei, is64, g); d = edge_at(ei, is64, (long long)E + g); }
    else       { s = d = (int)(g - E); }
    int pos = atomicAdd(&cur[d >> 7], 1);
    tmp[pos] = ((unsigned)s << 7) | (unsigned)(d & 127);
  }
}

#define MM_SMEM (32 * 136 * 2 + 128 * 4 + 128 * 4)  // Al + scl + sht = 9728 B

// MFMA matmul + es/ed via 9th B-tile (wave 0). smem: MM_SMEM bytes, 16-aligned.
__device__ __forceinline__ void mm_body(int blk, const void* xin, int packed,
    const float* stats, const float* gamma, const float* beta,
    const unsigned short* Bp, unsigned* hb, unsigned* linp,
    float* es, float* ed, int N, char* smem) {
  unsigned short* Al = (unsigned short*)smem;                  // 32*136
  float* scl_s = (float*)(smem + 8704);
  float* sht_s = (float*)(smem + 8704 + 512);
  int tid = threadIdx.x;
  int lane = tid & 63;
  int w = tid >> 6;
  int rowBase = blk * 32;

  if (tid < 128) {
    float s = 0.f, s2 = 0.f;
#pragma unroll
    for (int r = 0; r < 8; ++r) {
      s += stats[r * 256 + tid];
      s2 += stats[r * 256 + 128 + tid];
    }
    float inv_n = 1.0f / (float)N;
    float mu = s * inv_n;
    float var = s2 * inv_n - mu * mu;
    float rs = rsqrtf(var + BN_EPS);
    float sc = gamma[tid] * rs;
    scl_s[tid] = sc;
    sht_s[tid] = beta[tid] - mu * sc;
  }

  v8bf bfrag[2][8];
#pragma unroll
  for (int t = 0; t < 2; ++t)
#pragma unroll
    for (int s = 0; s < 8; ++s) {
      int fi = ((2 * w + t) * 8 + s) * 64 + lane;
      bfrag[t][s] = *(const v8bf*)&Bp[(size_t)fi * 8];
    }
  __syncthreads();

  if (!packed) {
    const float* x = (const float*)xin;
    for (int q = tid; q < 32 * 32; q += 256) {
      int r = q >> 5, k4 = (q & 31) * 4;
      int row = rowBase + r;
      float4 v = make_float4(0.f, 0.f, 0.f, 0.f);
      if (row < N) v = *(const float4*)&x[(size_t)row * 128 + k4];
      unsigned p0 = pack_bf16(v.x * scl_s[k4] + sht_s[k4], v.y * scl_s[k4 + 1] + sht_s[k4 + 1]);
      unsigned p1 = pack_bf16(v.z * scl_s[k4 + 2] + sht_s[k4 + 2], v.w * scl_s[k4 + 3] + sht_s[k4 + 3]);
      *(uint2*)&Al[r * 136 + k4] = make_uint2(p0, p1);
    }
  } else {
    const unsigned* xp = (const unsigned*)xin;
    for (int q = tid; q < 32 * 16; q += 256) {
      int r = q >> 4, g = q & 15;
      int row = rowBase + r;
      uint4 u = make_uint4(0u, 0u, 0u, 0u);
      if (row < N) u = *(const uint4*)&xp[(size_t)row * 64 + g * 4];
      int f = g * 8;
      uint4 o;
      o.x = pack_bf16(blo(u.x) * scl_s[f] + sht_s[f], bhi(u.x) * scl_s[f + 1] + sht_s[f + 1]);
      o.y = pack_bf16(blo(u.y) * scl_s[f + 2] + sht_s[f + 2], bhi(u.y) * scl_s[f + 3] + sht_s[f + 3]);
      o.z = pack_bf16(blo(u.z) * scl_s[f + 4] + sht_s[f + 4], bhi(u.z) * scl_s[f + 5] + sht_s[f + 5]);
      o.w = pack_bf16(blo(u.w) * scl_s[f + 6] + sht_s[f + 6], bhi(u.w) * scl_s[f + 7] + sht_s[f + 7]);
      *(uint4*)&Al[r * 136 + f] = o;
    }
  }
  __syncthreads();

  int m = lane & 31, half = lane >> 5;
  v8bf afrag[8];
#pragma unroll
  for (int s = 0; s < 8; ++s)
    afrag[s] = *(const v8bf*)&Al[m * 136 + s * 16 + half * 8];

  v16f acc0 = {}, acc1 = {};
#pragma unroll
  for (int s = 0; s < 8; ++s) {
    acc0 = __builtin_amdgcn_mfma_f32_32x32x16_bf16(afrag[s], bfrag[0][s], acc0, 0, 0, 0);
    acc1 = __builtin_amdgcn_mfma_f32_32x32x16_bf16(afrag[s], bfrag[1][s], acc1, 0, 0, 0);
  }

  v16f acc2 = {};
  if (w == 0) {
#pragma unroll
    for (int s = 0; s < 8; ++s) {
      v8bf besf = *(const v8bf*)&Bp[(size_t)((64 + s) * 64 + lane) * 8];
      acc2 = __builtin_amdgcn_mfma_f32_32x32x16_bf16(afrag[s], besf, acc2, 0, 0, 0);
    }
  }

  int mlo = half * 4;
  int t0 = 2 * w, t1 = 2 * w + 1;
#pragma unroll
  for (int r = 0; r < 16; ++r) {
    int row = (r & 3) + 8 * (r >> 2) + mlo;
    int node = rowBase + row;
    float a0 = acc0[r], a1 = acc1[r];
    float b0 = __shfl_xor(a0, 1, 64);
    float b1 = __shfl_xor(a1, 1, 64);
    if (node < N && !(lane & 1)) {
      if (t0 < 4) {
        hb[(size_t)node * 64 + (t0 * 16 + (m >> 1))] = pack_bf16(a0, b0);
        hb[(size_t)node * 64 + (t1 * 16 + (m >> 1))] = pack_bf16(a1, b1);
      } else {
        linp[(size_t)node * 64 + ((t0 - 4) * 16 + (m >> 1))] = pack_bf16(a0, b0);
        linp[(size_t)node * 64 + ((t1 - 4) * 16 + (m >> 1))] = pack_bf16(a1, b1);
      }
    }
    if (w == 0 && m < 4 && node < N) {
      float v = acc2[r];
      if (m < 2) es[2 * node + (m & 1)] = v;
      else       ed[2 * node + (m & 1)] = v;
    }
  }
}

// =================== kernels ===================

// K1: prep (Bp tiles 0-8, Wesed->tile8, layer-1 BN stats) UNION binA.
// blocks [0,34): weight prep; [34,1058): stats; [1058, 1058+nblk): binA.
__global__ __launch_bounds__(256) void k_prepA(
    const float* __restrict__ W1, const float* __restrict__ LW1,
    const float* __restrict__ W2, const float* __restrict__ LW2,
    const float* __restrict__ as1, const float* __restrict__ ad1,
    const float* __restrict__ as2, const float* __restrict__ ad2,
    const float* __restrict__ x, int N,
    unsigned short* __restrict__ Bp1, unsigned short* __restrict__ Bp2,
    float* __restrict__ stats1,
    const void* ei, int E, int M, int nb, int nblk, int* counts) {
  __shared__ __align__(16) int lds[1025];
  int blk = blockIdx.x;
  int tid = threadIdx.x;
  if (blk >= 1058) { binA_body(blk - 1058, ei, N, E, M, nb, nblk, counts, lds); return; }
  if (blk >= 34) {
    int b = blk - 34;  // 0..1023
    int f = tid & 127;
    int half = tid >> 7;
    float s = 0.f, s2 = 0.f;
    for (int r = b + half * 1024; r < N; r += 2048) {
      float v = x[(size_t)r * 128 + f];
      s += v; s2 += v * v;
    }
    float* rep = stats1 + (size_t)(b & 7) * 256;
    atomicAdd(&rep[f], s);
    atomicAdd(&rep[128 + f], s2);
    return;
  }
  if (blk >= 32) {
    // tile 8: es/ed columns in B-fragment order
    float (*wes)[4] = (float(*)[4])lds;  // 128x4 floats = 2 KB
    const float* W = (blk == 32) ? W1 : W2;
    const float* as_ = (blk == 32) ? as1 : as2;
    const float* ad_ = (blk == 32) ? ad1 : ad2;
    unsigned short* Bp = (blk == 32) ? Bp1 : Bp2;
#pragma unroll
    for (int it = 0; it < 2; ++it) {
      int k = tid & 127;
      int c = (tid >> 7) + 2 * it;
      const float* a = (c < 2) ? as_ : ad_;
      int hb2 = (c & 1) * 64;
      float sum = 0.f;
      for (int f = 0; f < 64; ++f) sum += W[k * 128 + hb2 + f] * a[hb2 + f];
      wes[k][c] = sum;
    }
    __syncthreads();
    for (int fr = tid; fr < 512; fr += 256) {
      int lane = fr & 63, s = fr >> 6;
      int n = lane & 31;
      int k0 = s * 16 + (lane >> 5) * 8;
      unsigned short tb[8];
#pragma unroll
      for (int j = 0; j < 8; ++j)
        tb[j] = bf16of((n < 4) ? wes[k0 + j][n] : 0.f);
      uint4 pk;
      pk.x = (unsigned)tb[0] | ((unsigned)tb[1] << 16);
      pk.y = (unsigned)tb[2] | ((unsigned)tb[3] << 16);
      pk.z = (unsigned)tb[4] | ((unsigned)tb[5] << 16);
      pk.w = (unsigned)tb[6] | ((unsigned)tb[7] << 16);
      int fi = (64 + s) * 64 + lane;
      *(uint4*)&Bp[(size_t)fi * 8] = pk;
    }
    return;
  }
  const float* W  = (blk < 16) ? W1 : W2;
  const float* LW = (blk < 16) ? LW1 : LW2;
  unsigned short* Bp = (blk < 16) ? Bp1 : Bp2;
  int fi = (blk & 15) * 256 + tid;  // 4096 frags (tiles 0-7)
  int lane = fi & 63, s = (fi >> 6) & 7, t = fi >> 9;
  int n = t * 32 + (lane & 31);
  int k0 = s * 16 + (lane >> 5) * 8;
  unsigned short tb[8];
#pragma unroll
  for (int j = 0; j < 8; ++j) {
    int k = k0 + j;
    float v = (n < 128) ? W[k * 128 + n] : LW[k * 128 + (n - 128)];
    tb[j] = bf16of(v);
  }
  uint4 pk;
  pk.x = (unsigned)tb[0] | ((unsigned)tb[1] << 16);
  pk.y = (unsigned)tb[2] | ((unsigned)tb[3] << 16);
  pk.z = (unsigned)tb[4] | ((unsigned)tb[5] << 16);
  pk.w = (unsigned)tb[6] | ((unsigned)tb[7] << 16);
  *(uint4*)&Bp[(size_t)fi * 8] = pk;
}

// scanA: per-bucket (row) exclusive scan of its nblk chunk-counts, in-place;
// writes rowTotal[j]. 391 blocks run in parallel -- no serial 79K scan.
__global__ __launch_bounds__(256) void k_scanA(int* __restrict__ counts, int nblk,
                                               int* __restrict__ rowTotal) {
  __shared__ int part[256];
  int tid = threadIdx.x;
  int j = blockIdx.x;
  int* row = counts + (size_t)j * nblk;
  int per = (nblk + 255) / 256;
  int lo = tid * per;
  int hi = lo + per; if (hi > nblk) hi = nblk;
  int s = 0;
  for (int i = lo; i < hi; ++i) s += row[i];
  part[tid] = s;
  __syncthreads();
  for (int off = 1; off < 256; off <<= 1) {
    int add = (tid >= off) ? part[tid - off] : 0;
    __syncthreads();
    part[tid] += add;
    __syncthreads();
  }
  int run = (tid == 0) ? 0 : part[tid - 1];
  for (int i = lo; i < hi; ++i) {
    int c = row[i];
    row[i] = run;
    run += c;
  }
  if (tid == 0) rowTotal[j] = part[255];
}

// scanB: exclusive scan of nb bucket totals -> bucketBase; bucketBase[nb]=M.
__global__ __launch_bounds__(512) void k_scanB(const int* __restrict__ rowTotal, int nb,
                                               int M, int* __restrict__ bucketBase) {
  __shared__ int part[512];
  int tid = threadIdx.x;
  int per = (nb + 511) / 512;
  int lo = tid * per;
  int hi = lo + per; if (hi > nb) hi = nb;
  int s = 0;
  for (int i = lo; i < hi; ++i) s += rowTotal[i];
  part[tid] = s;
  __syncthreads();
  for (int off = 1; off < 512; off <<= 1) {
    int add = (tid >= off) ? part[tid - off] : 0;
    __syncthreads();
    part[tid] += add;
    __syncthreads();
  }
  int run = (tid == 0) ? 0 : part[tid - 1];
  for (int i = lo; i < hi; ++i) {
    bucketBase[i] = run;
    run += rowTotal[i];
  }
  if (tid == 0) bucketBase[nb] = M;
}

// K3: layer-1 MFMA matmul UNION binC. blocks [0,gmm): mm; [gmm, gmm+nblk): binC.
__global__ __launch_bounds__(256) void k_mmC(
    const void* __restrict__ xin, int packed,
    const float* __restrict__ stats, const float* __restrict__ gamma, const float* __restrict__ beta,
    const unsigned short* __restrict__ Bp,
    unsigned* __restrict__ hb, unsigned* __restrict__ linp,
    float* __restrict__ es, float* __restrict__ ed, int N, int gmm,
    const void* ei, int E, int M, int nb, int nblk, const int* counts,
    const int* bucketBase, unsigned* tmp) {
  __shared__ __align__(16) char smem[MM_SMEM];
  int blk = blockIdx.x;
  if (blk < gmm) {
    mm_body(blk, xin, packed, stats, gamma, beta, Bp, hb, linp, es, ed, N, smem);
  } else {
    binC_body(blk - gmm, ei, N, E, M, nb, nblk, counts, bucketBase, tmp, (int*)smem);
  }
}

// standalone mm (layer 2)
__global__ __launch_bounds__(256) void k_mm(
    const void* __restrict__ xin, int packed,
    const float* __restrict__ stats, const float* __restrict__ gamma, const float* __restrict__ beta,
    const unsigned short* __restrict__ Bp,
    unsigned* __restrict__ hb, unsigned* __restrict__ linp,
    float* __restrict__ es, float* __restrict__ ed, int N) {
  __shared__ __align__(16) char smem[MM_SMEM];
  mm_body(blockIdx.x, xin, packed, stats, gamma, beta, Bp, hb, linp, es, ed, N, smem);
}

// binD: per-bucket (128 dsts) counting sort -> rowptr + col.
__global__ __launch_bounds__(256) void k_binD(const unsigned* __restrict__ tmp,
                                              const int* __restrict__ bucketBase,
                                              int nb, int M, int N,
                                              int* __restrict__ rowptr, int* __restrict__ col) {
  __shared__ int scn[128];
  __shared__ int cur[128];
  int tid = threadIdx.x;
  int j = blockIdx.x;
  int base = bucketBase[j];
  int endv = bucketBase[j + 1];
  int bc = endv - base;
  if (tid < 128) scn[tid] = 0;
  __syncthreads();
  for (int i = tid; i < bc; i += 256) atomicAdd(&scn[tmp[base + i] & 127], 1);
  __syncthreads();
  int v = (tid < 128) ? scn[tid] : 0;
  __syncthreads();
  for (int off = 1; off < 128; off <<= 1) {
    int add = (tid >= off && tid < 128) ? scn[tid - off] : 0;
    __syncthreads();
    if (tid < 128) scn[tid] += add;
    __syncthreads();
  }
  if (tid < 128) {
    int excl = scn[tid] - v;
    int d = (j << 7) + tid;
    if (d < N) rowptr[d] = base + excl;
    cur[tid] = base + excl;
  }
  __syncthreads();
  for (int i = tid; i < bc; i += 256) {
    unsigned w = tmp[base + i];
    int pos = atomicAdd(&cur[w & 127], 1);
    col[pos] = (int)(w >> 7);
  }
  if (j == nb - 1 && tid == 0) rowptr[N] = M;
}

// ---------- BatchNorm stats for packed-bf16 input (layers 2/3) ----------
__global__ __launch_bounds__(128) void k_bnstats(const unsigned* __restrict__ xp,
                                                 int N, float* sums) {
  int f = threadIdx.x;
  int q = f >> 1, hi = f & 1;
  float s = 0.f, s2 = 0.f;
  for (int r = blockIdx.x; r < N; r += gridDim.x) {
    unsigned u = xp[(size_t)r * 64 + q];
    float v = hi ? bhi(u) : blo(u);
    s += v; s2 += v * v;
  }
  float* rep = sums + (size_t)(blockIdx.x & 7) * 256;
  atomicAdd(&rep[f], s);
  atomicAdd(&rep[128 + f], s2);
}

// ---------- single-pass edge aggregation + combine; one wave per dst ----------
// Phase-split + perm/dot2; 16 edges/iter main loop (4 gathers in flight).
__global__ __launch_bounds__(256) void k_agg(
    const int* __restrict__ rowptr, const int* __restrict__ col,
    const float* __restrict__ es, const float* __restrict__ ed,
    const unsigned* __restrict__ hb, const unsigned* __restrict__ linp,
    const float* __restrict__ lb, const float* __restrict__ gb,
    unsigned* __restrict__ xoutp, int N) {
  __shared__ unsigned short phb[4][2][64];  // p (bf16) per head, per wave
  __shared__ unsigned obuf[4][64];          // hb dword offsets, per wave
  int lane = threadIdx.x & 63;
  int w = threadIdx.x >> 6;
  int d = blockIdx.x * 4 + w;
  if (d >= N) return;
  int start = rowptr[d], end = rowptr[d + 1];
  v2f edv = *(const v2f*)&ed[2 * d];
  int q = lane >> 4;   // edge-pair group 0..3
  int m = lane & 15;   // feats 8m..8m+7
  int head_hi = m >= 8;
  v2f zero = {0.f, 0.f};
  v2f lk = {LEAKY, LEAKY};

  v2f acc[4] = {zero, zero, zero, zero};
  v2f spv = zero;                       // per-lane softmax denom partial (both heads)
  unsigned short* ph = &phb[w][0][0];
  unsigned* oo = obuf[w];
  int hoff = head_hi ? 64 : 0;

  for (int base = start; base < end; base += 64) {
    int cnt = end - base; if (cnt > 64) cnt = 64;
    // ---- phase 1: p for up to 64 edges, one per lane (exp computed once/edge) ----
    {
      int valid = lane < cnt;
      int s = col[valid ? base + lane : base];
      v2f ev = *(const v2f*)&es[2 * s];
      v2f e = ev + edv;
      v2f le = __builtin_elementwise_max(e, zero) + lk * __builtin_elementwise_min(e, zero);
      v2f p; p.x = __expf(le.x); p.y = __expf(le.y);
      if (!valid) p = zero;             // zero-pad slots [cnt,64): no contribution
      spv += p;
      ph[lane] = bf16of(p.x);
      ph[64 + lane] = bf16of(p.y);
      oo[lane] = (unsigned)s * 64u;     // dword offset of hb row (clamped s is valid)
    }
    // same wave: LDS writes above are ordered before reads below (no barrier needed)
    // ---- phase 2 main: 16 edges/iter, 4 gathers in flight per lane ----
    int i = 0;
    for (; i + 16 <= cnt; i += 16) {
      int e1 = i + 2 * q;               // pair A
      int e2 = i + 8 + 2 * q;           // pair B
      unsigned fpA = *(const unsigned*)&ph[hoff + e1];
      unsigned fpB = *(const unsigned*)&ph[hoff + e2];
      uint2 oA = *(const uint2*)&oo[e1];
      uint2 oB = *(const uint2*)&oo[e2];
      uint4 u1 = *(const uint4*)&hb[(size_t)oA.x + m * 4];
      uint4 u2 = *(const uint4*)&hb[(size_t)oA.y + m * 4];
      uint4 u3 = *(const uint4*)&hb[(size_t)oB.x + m * 4];
      uint4 u4 = *(const uint4*)&hb[(size_t)oB.y + m * 4];
      acc[0].x = dot2bf(fpA, permlo(u1.x, u2.x), acc[0].x);
      acc[0].y = dot2bf(fpA, permhi(u1.x, u2.x), acc[0].y);
      acc[1].x = dot2bf(fpA, permlo(u1.y, u2.y), acc[1].x);
      acc[1].y = dot2bf(fpA, permhi(u1.y, u2.y), acc[1].y);
      acc[2].x = dot2bf(fpA, permlo(u1.z, u2.z), acc[2].x);
      acc[2].y = dot2bf(fpA, permhi(u1.z, u2.z), acc[2].y);
      acc[3].x = dot2bf(fpA, permlo(u1.w, u2.w), acc[3].x);
      acc[3].y = dot2bf(fpA, permhi(u1.w, u2.w), acc[3].y);
      acc[0].x = dot2bf(fpB, permlo(u3.x, u4.x), acc[0].x);
      acc[0].y = dot2bf(fpB, permhi(u3.x, u4.x), acc[0].y);
      acc[1].x = dot2bf(fpB, permlo(u3.y, u4.y), acc[1].x);
      acc[1].y = dot2bf(fpB, permhi(u3.y, u4.y), acc[1].y);
      acc[2].x = dot2bf(fpB, permlo(u3.z, u4.z), acc[2].x);
      acc[2].y = dot2bf(fpB, permhi(u3.z, u4.z), acc[2].y);
      acc[3].x = dot2bf(fpB, permlo(u3.w, u4.w), acc[3].x);
      acc[3].y = dot2bf(fpB, permhi(u3.w, u4.w), acc[3].y);
    }
    // ---- phase 2 remainder: 8 edges/iter (p zero-padded beyond cnt) ----
    for (; i < cnt; i += 8) {
      int e1 = i + 2 * q;               // e1 <= 63 always (i <= 56)
      unsigned fp = *(const unsigned*)&ph[hoff + e1];
      uint2 ofs = *(const uint2*)&oo[e1];
      uint4 u1 = *(const uint4*)&hb[(size_t)ofs.x + m * 4];
      uint4 u2 = *(const uint4*)&hb[(size_t)ofs.y + m * 4];
      acc[0].x = dot2bf(fp, permlo(u1.x, u2.x), acc[0].x);
      acc[0].y = dot2bf(fp, permhi(u1.x, u2.x), acc[0].y);
      acc[1].x = dot2bf(fp, permlo(u1.y, u2.y), acc[1].x);
      acc[1].y = dot2bf(fp, permhi(u1.y, u2.y), acc[1].y);
      acc[2].x = dot2bf(fp, permlo(u1.z, u2.z), acc[2].x);
      acc[2].y = dot2bf(fp, permhi(u1.z, u2.z), acc[2].y);
      acc[3].x = dot2bf(fp, permlo(u1.w, u2.w), acc[3].x);
      acc[3].y = dot2bf(fp, permhi(u1.w, u2.w), acc[3].y);
    }
  }
  // reduce acc across quarters
#pragma unroll
  for (int k = 0; k < 4; ++k) {
    acc[k].x += __shfl_xor(acc[k].x, 16, 64);
    acc[k].x += __shfl_xor(acc[k].x, 32, 64);
    acc[k].y += __shfl_xor(acc[k].y, 16, 64);
    acc[k].y += __shfl_xor(acc[k].y, 32, 64);
  }
  // reduce softmax denom across all 64 lanes (one edge per lane in phase 1)
#pragma unroll
  for (int o = 1; o < 64; o <<= 1) {
    spv.x += __shfl_xor(spv.x, o, 64);
    spv.y += __shfl_xor(spv.y, o, 64);
  }

  if (q == 0) {
    float inv = 1.0f / (head_hi ? spv.y : spv.x);
    uint4 lv = *(const uint4*)&linp[(size_t)d * 64 + m * 4];
    int f8 = 8 * m;
    float4 lb0 = *(const float4*)&lb[f8], lb1 = *(const float4*)&lb[f8 + 4];
    float4 gb0 = *(const float4*)&gb[f8], gb1 = *(const float4*)&gb[f8 + 4];
    float v0 = blo(lv.x) + lb0.x + acc[0].x * inv + gb0.x;
    float v1 = bhi(lv.x) + lb0.y + acc[0].y * inv + gb0.y;
    float v2 = blo(lv.y) + lb0.z + acc[1].x * inv + gb0.z;
    float v3 = bhi(lv.y) + lb0.w + acc[1].y * inv + gb0.w;
    float v4 = blo(lv.z) + lb1.x + acc[2].x * inv + gb1.x;
    float v5 = bhi(lv.z) + lb1.y + acc[2].y * inv + gb1.y;
    float v6 = blo(lv.w) + lb1.z + acc[3].x * inv + gb1.z;
    float v7 = bhi(lv.w) + lb1.w + acc[3].y * inv + gb1.w;
    v0 = v0 > 0.f ? v0 : 0.f; v1 = v1 > 0.f ? v1 : 0.f;
    v2 = v2 > 0.f ? v2 : 0.f; v3 = v3 > 0.f ? v3 : 0.f;
    v4 = v4 > 0.f ? v4 : 0.f; v5 = v5 > 0.f ? v5 : 0.f;
    v6 = v6 > 0.f ? v6 : 0.f; v7 = v7 > 0.f ? v7 : 0.f;
    uint4 o;
    o.x = pack_bf16(v0, v1); o.y = pack_bf16(v2, v3);
    o.z = pack_bf16(v4, v5); o.w = pack_bf16(v6, v7);
    *(uint4*)&xoutp[(size_t)d * 64 + m * 4] = o;
  }
}

// ---------- layer 3: BN(inline, 8-replica stats) + tiny matmul + packed node data ----------
// Writes pk4[n] = {es3_n, hc0, hc1, 0} (one 16B gather target for agg3) + ed3, lin3.
__global__ __launch_bounds__(256) void k_l3node(
    const unsigned* __restrict__ xp,
    const float* __restrict__ stats, const float* __restrict__ gamma, const float* __restrict__ beta,
    const float* __restrict__ W3, const float* __restrict__ LW3,
    const float* __restrict__ as3, const float* __restrict__ ad3,
    float4* __restrict__ pk4, float* lin3, float* ed3, int N) {
  int lane = threadIdx.x & 63;
  int n = blockIdx.x * 4 + (threadIdx.x >> 6);
  if (n >= N) return;
  float inv_n = 1.0f / (float)N;
  int f0 = lane, f1 = 64 + lane;
  float su0 = 0.f, sq0 = 0.f, su1 = 0.f, sq1 = 0.f;
#pragma unroll
  for (int r = 0; r < 8; ++r) {
    su0 += stats[r * 256 + f0];  sq0 += stats[r * 256 + 128 + f0];
    su1 += stats[r * 256 + f1];  sq1 += stats[r * 256 + 128 + f1];
  }
  float mu0 = su0 * inv_n;
  float var0 = sq0 * inv_n - mu0 * mu0;
  float rs0 = rsqrtf(var0 + BN_EPS);
  float sc0 = gamma[f0] * rs0, sh0 = beta[f0] - mu0 * sc0;
  float mu1 = su1 * inv_n;
  float var1 = sq1 * inv_n - mu1 * mu1;
  float rs1 = rsqrtf(var1 + BN_EPS);
  float sc1 = gamma[f1] * rs1, sh1 = beta[f1] - mu1 * sc1;

  unsigned ua = xp[(size_t)n * 64 + (lane >> 1)];
  unsigned ub = xp[(size_t)n * 64 + 32 + (lane >> 1)];
  float xv0 = (lane & 1) ? bhi(ua) : blo(ua);
  float xv1 = (lane & 1) ? bhi(ub) : blo(ub);
  float xn0 = xv0 * sc0 + sh0;
  float xn1 = xv1 * sc1 + sh1;

  float2 w0 = *(const float2*)&W3[lane * 2];
  float2 w1 = *(const float2*)&W3[(64 + lane) * 2];
  float2 l0 = *(const float2*)&LW3[lane * 2];
  float2 l1 = *(const float2*)&LW3[(64 + lane) * 2];
  float hc0 = wsum(xn0 * w0.x + xn1 * w1.x);
  float hc1 = wsum(xn0 * w0.y + xn1 * w1.y);
  float lc0 = wsum(xn0 * l0.x + xn1 * l1.x);
  float lc1 = wsum(xn0 * l0.y + xn1 * l1.y);
  if (lane == 0) {
    float e_s = hc0 * as3[0] + hc1 * as3[1];
    pk4[n] = make_float4(e_s, hc0, hc1, 0.f);
    lin3[2 * n] = lc0; lin3[2 * n + 1] = lc1;
    ed3[n] = hc0 * ad3[0] + hc1 * ad3[1];
  }
}

// ---------- layer 3 edge aggregation + final output ----------
// 16 lanes per dst (4 dsts/wave, 16/block): ~4x lane utilization at deg~33,
// and one packed float4 gather per edge (es3+h3 fused) instead of two.
__global__ __launch_bounds__(256) void k_agg3(
    const int* __restrict__ rowptr, const int* __restrict__ col,
    const float4* __restrict__ pk4, const float* __restrict__ ed3,
    const float* __restrict__ lin3,
    const float* __restrict__ lb3, const float* __restrict__ gb3,
    float* __restrict__ out, int N) {
  int tid = threadIdx.x;
  int d = blockIdx.x * 16 + (tid >> 4);
  int t = tid & 15;
  if (d >= N) return;
  int start = rowptr[d], end = rowptr[d + 1];
  float edd = ed3[d];
  float ps = 0.f, a0 = 0.f, a1 = 0.f;
  for (int i = start + t; i < end; i += 16) {
    int s = col[i];
    float4 g = pk4[s];
    float e = g.x + edd; e = e > 0.f ? e : LEAKY * e;
    float p = __expf(e);
    ps += p; a0 += p * g.y; a1 += p * g.z;
  }
  // reduce across the 16-lane group (groups are 16-aligned within the wave)
#pragma unroll
  for (int o = 1; o < 16; o <<= 1) {
    ps += __shfl_xor(ps, o, 64);
    a0 += __shfl_xor(a0, o, 64);
    a1 += __shfl_xor(a1, o, 64);
  }
  if (t < 2) {
    float a = (t == 0 ? a0 : a1) / ps;
    float v = lin3[2 * d + t] + lb3[t] + a + gb3[t];
    out[2 * d + t] = v > 0.f ? v : 0.f;
  }
}

extern "C" void kernel_launch(void* const* d_in, const int* in_sizes, int n_in,
                              void* d_out, int out_size, void* d_ws, size_t ws_size,
                              hipStream_t stream) {
  const float* x   = (const float*)d_in[0];
  const void*  ei  = d_in[1];
  const float* W1  = (const float*)d_in[2];
  const float* as1 = (const float*)d_in[3];
  const float* ad1 = (const float*)d_in[4];
  const float* gb1 = (const float*)d_in[5];
  const float* lw1 = (const float*)d_in[6];
  const float* lb1 = (const float*)d_in[7];
  const float* bg1 = (const float*)d_in[8];
  const float* bb1 = (const float*)d_in[9];
  const float* W2  = (const float*)d_in[10];
  const float* as2 = (const float*)d_in[11];
  const float* ad2 = (const float*)d_in[12];
  const float* gb2 = (const float*)d_in[13];
  const float* lw2 = (const float*)d_in[14];
  const float* lb2 = (const float*)d_in[15];
  const float* bg2 = (const float*)d_in[16];
  const float* bb2 = (const float*)d_in[17];
  const float* W3  = (const float*)d_in[18];
  const float* as3 = (const float*)d_in[19];
  const float* ad3 = (const float*)d_in[20];
  const float* gb3 = (const float*)d_in[21];
  const float* lw3 = (const float*)d_in[22];
  const float* lb3 = (const float*)d_in[23];
  const float* bg3 = (const float*)d_in[24];
  const float* bb3 = (const float*)d_in[25];
  float* out = (float*)d_out;

  int N = in_sizes[0] / 128;
  int E = in_sizes[1] / 2;
  int M = E + N;
  int nb = (N + 127) >> 7;            // 128-wide buckets
  int nblk = (M + BCHUNK - 1) / BCHUNK;

  char* wsp = (char*)d_ws;
  size_t off = 0;
  auto alloc = [&](size_t bytes) -> void* {
    void* p = wsp + off;
    off = (off + bytes + 255) & ~(size_t)255;
    return p;
  };
  int* rowptr   = (int*)alloc(((size_t)N + 1) * 4);
  int* col      = (int*)alloc((size_t)M * 4);
  unsigned* tmp = (unsigned*)alloc((size_t)M * 4);
  int* counts   = (int*)alloc(((size_t)nb * nblk + 1) * 4);
  int* rowTotal = (int*)alloc((size_t)nb * 4);
  int* bucketBase = (int*)alloc(((size_t)nb + 1) * 4);
  float* st1    = (float*)alloc(8 * 256 * 4);
  float* st2    = (float*)alloc(8 * 256 * 4);
  float* st3    = (float*)alloc(8 * 256 * 4);
  unsigned short* Bp1 = (unsigned short*)alloc(4608 * 16);  // 9 tiles
  unsigned short* Bp2 = (unsigned short*)alloc(4608 * 16);
  unsigned* hbp  = (unsigned*)alloc((size_t)N * 64 * 4);
  unsigned* linp = (unsigned*)alloc((size_t)N * 64 * 4);
  unsigned* x2p  = (unsigned*)alloc((size_t)N * 64 * 4);
  float* es    = (float*)alloc((size_t)N * 2 * 4);
  float* edb   = (float*)alloc((size_t)N * 2 * 4);
  float4* pk4  = (float4*)alloc((size_t)N * 16);
  float* lin3  = (float*)alloc((size_t)N * 2 * 4);
  float* ed3   = (float*)alloc((size_t)N * 4);
  (void)ws_size; (void)n_in; (void)out_size;

  hipMemsetAsync(st1, 0, 3 * 8 * 256 * 4, stream);  // st1,st2,st3 contiguous

  int gnode = (N + 3) / 4;
  int gmm = (N + 31) / 32;
  int gagg3 = (N + 15) / 16;

  // K1: weight prep + layer-1 BN stats + binA (merged, independent work)
  k_prepA<<<1058 + nblk, 256, 0, stream>>>(W1, lw1, W2, lw2, as1, ad1, as2, ad2,
                                           x, N, Bp1, Bp2, st1,
                                           ei, E, M, nb, nblk, counts);
  // hierarchical scan: per-bucket parallel scan + tiny bucket-base scan
  k_scanA<<<nb, 256, 0, stream>>>(counts, nblk, rowTotal);
  k_scanB<<<1, 512, 0, stream>>>(rowTotal, nb, M, bucketBase);
  // K3: layer-1 matmul + binC (merged, independent work)
  k_mmC<<<gmm + nblk, 256, 0, stream>>>(x, 0, st1, bg1, bb1, Bp1, hbp, linp, es, edb, N,
                                        gmm, ei, E, M, nb, nblk, counts, bucketBase, tmp);
  k_binD<<<nb, 256, 0, stream>>>(tmp, bucketBase, nb, M, N, rowptr, col);

  // ---- layer 1 aggregation ----
  k_agg<<<gnode, 256, 0, stream>>>(rowptr, col, es, edb, hbp, linp, lb1, gb1, x2p, N);

  // ---- layer 2 ----
  k_bnstats<<<1024, 128, 0, stream>>>(x2p, N, st2);
  k_mm<<<gmm, 256, 0, stream>>>(x2p, 1, st2, bg2, bb2, Bp2, hbp, linp, es, edb, N);
  k_agg<<<gnode, 256, 0, stream>>>(rowptr, col, es, edb, hbp, linp, lb2, gb2, x2p, N);

  // ---- layer 3 ----
  k_bnstats<<<1024, 128, 0, stream>>>(x2p, N, st3);
  k_l3node<<<gnode, 256, 0, stream>>>(x2p, st3, bg3, bb3, W3, lw3, as3, ad3,
                                      pk4, lin3, ed3, N);
  k_agg3<<<gagg3, 256, 0, stream>>>(rowptr, col, pk4, ed3, lin3, lb3, gb3, out, N);
}